// Round 2
// baseline (11535.492 us; speedup 1.0000x reference)
//
#include <hip/hip_runtime.h>
#include <hip/hip_bf16.h>

#define DM 512
#define DFF 2048
#define NB 4
#define SEQ 2048
#define NH 8
#define HD 64
#define NL 12
#define NT 400
#define MR (NB*SEQ)      // 8192 rows
#define CHK 64           // attention chunk length
#define NCH (SEQ/CHK)    // 32 chunks
#define NBH (NB*NH)      // 32 (b,h) pairs

// h[row, :] = emb[x[row]] * sqrt(512) + sinusoidal_pe(row % SEQ, :)
__global__ __launch_bounds__(256) void embed_kernel(const int* __restrict__ x,
                                                    const float* __restrict__ emb,
                                                    float* __restrict__ h)
{
    int row = blockIdx.x;
    int s = row & (SEQ - 1);
    int tok = x[row];
    int j = threadIdx.x;               // handles elements 2j, 2j+1
    float2 ev = *(const float2*)(emb + (size_t)tok * DM + 2 * j);
    const float scale = 22.627416997969522f;           // sqrt(512)
    float dv = expf((float)(2 * j) * (-9.210340371976184f / 512.0f)); // exp(2j * -ln(1e4)/512)
    float ang = (float)s * dv;
    float2 o;
    o.x = ev.x * scale + sinf(ang);
    o.y = ev.y * scale + cosf(ang);
    *(float2*)(h + (size_t)row * DM + 2 * j) = o;
}

// C[M,N] = A[M,K] @ W[K,N] + bias (+res) (relu?) ; all fp32.
__global__ __launch_bounds__(256) void gemm_kernel(
    const float* __restrict__ A, const float* __restrict__ W,
    const float* __restrict__ bias, const float* __restrict__ res,
    float* __restrict__ C,
    int N, int K, int relu)
{
    __shared__ float As[16][64];   // transposed: As[k][m]
    __shared__ float Ws[16][64];
    const int tid = threadIdx.x;
    const int m0 = blockIdx.x << 6;
    const int n0 = blockIdx.y << 6;
    const int arow = tid >> 2, acol = (tid & 3) << 2;
    const int wrow = tid >> 4, wcol = (tid & 15) << 2;
    const int tx = tid & 15, ty = tid >> 4;
    float acc[4][4] = {};
    const float* Ap = A + (size_t)(m0 + arow) * K + acol;
    for (int k0 = 0; k0 < K; k0 += 16) {
        float4 av = *(const float4*)(Ap + k0);
        As[acol + 0][arow] = av.x; As[acol + 1][arow] = av.y;
        As[acol + 2][arow] = av.z; As[acol + 3][arow] = av.w;
        int wn = n0 + wcol;
        const float* wp = W + (size_t)(k0 + wrow) * N + wn;
        float4 wv;
        if (wn + 3 < N) {
            wv = *(const float4*)wp;
        } else {
            wv.x = (wn + 0 < N) ? wp[0] : 0.f;
            wv.y = (wn + 1 < N) ? wp[1] : 0.f;
            wv.z = (wn + 2 < N) ? wp[2] : 0.f;
            wv.w = (wn + 3 < N) ? wp[3] : 0.f;
        }
        Ws[wrow][wcol + 0] = wv.x; Ws[wrow][wcol + 1] = wv.y;
        Ws[wrow][wcol + 2] = wv.z; Ws[wrow][wcol + 3] = wv.w;
        __syncthreads();
#pragma unroll
        for (int kk = 0; kk < 16; ++kk) {
            float4 a4 = *(const float4*)&As[kk][ty << 2];
            float4 b4 = *(const float4*)&Ws[kk][tx << 2];
            acc[0][0] += a4.x * b4.x; acc[0][1] += a4.x * b4.y;
            acc[0][2] += a4.x * b4.z; acc[0][3] += a4.x * b4.w;
            acc[1][0] += a4.y * b4.x; acc[1][1] += a4.y * b4.y;
            acc[1][2] += a4.y * b4.z; acc[1][3] += a4.y * b4.w;
            acc[2][0] += a4.z * b4.x; acc[2][1] += a4.z * b4.y;
            acc[2][2] += a4.z * b4.z; acc[2][3] += a4.z * b4.w;
            acc[3][0] += a4.w * b4.x; acc[3][1] += a4.w * b4.y;
            acc[3][2] += a4.w * b4.z; acc[3][3] += a4.w * b4.w;
        }
        __syncthreads();
    }
#pragma unroll
    for (int i = 0; i < 4; ++i) {
        int m = m0 + (ty << 2) + i;
#pragma unroll
        for (int j = 0; j < 4; ++j) {
            int n = n0 + (tx << 2) + j;
            if (n < N) {
                float vv = acc[i][j] + bias[n];
                if (res) vv += res[(size_t)m * N + n];
                if (relu) vv = fmaxf(vv, 0.f);
                C[(size_t)m * N + n] = vv;
            }
        }
    }
}

// elu(x)+1 applied in place to q and k feature buffers
__global__ __launch_bounds__(256) void feat_kernel(float* __restrict__ q, float* __restrict__ k)
{
    size_t i = (size_t)blockIdx.x * 256 + threadIdx.x;
    float a = q[i]; q[i] = a > 0.f ? a + 1.f : expf(a);
    float b = k[i]; k[i] = b > 0.f ? b + 1.f : expf(b);
}

// Per (b,h,chunk): Ssum[d][e] = sum_t k[t][d]*v[t][e];  zsum[d] = sum_t k[t][d]
__global__ __launch_bounds__(256) void chunksum_kernel(
    const float* __restrict__ kf, const float* __restrict__ v,
    float* __restrict__ Ssum, float* __restrict__ zsum)
{
    __shared__ float Ks[CHK][HD + 1];
    __shared__ float Vs[CHK][HD + 1];
    int blk = blockIdx.x;               // b*NH*NCH + h*NCH + c
    int c = blk % NCH; int bh = blk / NCH;
    int hh = bh % NH;  int b = bh / NH;
    const float* kbase = kf + ((size_t)b * SEQ + (size_t)c * CHK) * DM + hh * HD;
    const float* vbase = v  + ((size_t)b * SEQ + (size_t)c * CHK) * DM + hh * HD;
    int tid = threadIdx.x;
    int e = tid & 63, g4 = tid >> 6;
#pragma unroll
    for (int i = 0; i < 16; ++i) {
        int t = g4 + 4 * i;
        Ks[t][e] = kbase[(size_t)t * DM + e];
        Vs[t][e] = vbase[(size_t)t * DM + e];
    }
    __syncthreads();
    float sacc[16];
#pragma unroll
    for (int i = 0; i < 16; ++i) sacc[i] = 0.f;
    for (int t = 0; t < CHK; ++t) {
        float vv = Vs[t][e];
#pragma unroll
        for (int i = 0; i < 16; ++i) sacc[i] += Ks[t][g4 + 4 * i] * vv;
    }
    float* So = Ssum + (size_t)blk * (HD * HD);
#pragma unroll
    for (int i = 0; i < 16; ++i) So[(g4 + 4 * i) * HD + e] = sacc[i];
    if (tid < 64) {
        float z = 0.f;
        for (int t = 0; t < CHK; ++t) z += Ks[t][tid];
        zsum[(size_t)blk * HD + tid] = z;
    }
}

// Exclusive prefix over chunks (per (b,h), per state entry)
__global__ __launch_bounds__(256) void prefix_kernel(
    const float* __restrict__ Ssum, float* __restrict__ Spre,
    const float* __restrict__ zsum, float* __restrict__ zpre)
{
    int bh = blockIdx.x >> 4;
    int eg = blockIdx.x & 15;
    int entry = (eg << 8) + threadIdx.x;     // 0..4095
    size_t base = (size_t)bh * NCH * (HD * HD) + entry;
    float pre = 0.f;
    for (int c = 0; c < NCH; ++c) {
        Spre[base + (size_t)c * (HD * HD)] = pre;
        pre += Ssum[base + (size_t)c * (HD * HD)];
    }
    if (eg == 0 && threadIdx.x < 64) {
        size_t zb = (size_t)bh * NCH * HD + threadIdx.x;
        float zp = 0.f;
        for (int c = 0; c < NCH; ++c) { zpre[zb + c * HD] = zp; zp += zsum[zb + c * HD]; }
    }
}

// Per (b,h,chunk): out[t] = (Q[t]@Spre + sum_{u<=t}(Q[t].K[u]) V[u]) / (Q[t].zpre + sum_{u<=t} Q[t].K[u] + eps)
// LDS: K-tile region is reused for the 64x64 score matrix after phase A (K dead).
__global__ __launch_bounds__(256) void attn_kernel(
    const float* __restrict__ qf, const float* __restrict__ kf,
    const float* __restrict__ v, const float* __restrict__ Spre,
    const float* __restrict__ zpre, float* __restrict__ out)
{
    __shared__ float Qs[CHK][HD + 1];
    __shared__ float Ks[CHK][HD + 1];   // phase A: K-tile; phase B: scores (64*64 floats)
    __shared__ float Vs[CHK][HD + 1];
    __shared__ float zs[HD];
    float* Asc = &Ks[0][0];             // reuse: Asc[t*64+u]
    int blk = blockIdx.x;
    int c = blk % NCH; int bh = blk / NCH;
    int hh = bh % NH;  int b = bh / NH;
    int tid = threadIdx.x;
    size_t rowbase = ((size_t)b * SEQ + (size_t)c * CHK) * DM + hh * HD;
    int e = tid & 63, g4 = tid >> 6;
#pragma unroll
    for (int i = 0; i < 16; ++i) {
        int t = g4 + 4 * i;
        Qs[t][e] = qf[rowbase + (size_t)t * DM + e];
        Ks[t][e] = kf[rowbase + (size_t)t * DM + e];
        Vs[t][e] = v [rowbase + (size_t)t * DM + e];
    }
    if (tid < 64) zs[tid] = zpre[((size_t)bh * NCH + c) * HD + tid];
    __syncthreads();
    // Phase A: scores sdot[i] = Q[t=4i+g4] . K[e] into registers
    float sdot[16];
#pragma unroll
    for (int i = 0; i < 16; ++i) {
        int t = 4 * i + g4;
        float sd = 0.f;
#pragma unroll
        for (int d = 0; d < HD; ++d) sd += Qs[t][d] * Ks[e][d];
        sdot[i] = sd;
    }
    __syncthreads();   // K reads done; now overwrite K region with scores
#pragma unroll
    for (int i = 0; i < 16; ++i) Asc[(4 * i + g4) * CHK + e] = sdot[i];
    __syncthreads();
    // Phase B: inter-chunk (Q @ Spre, Q . zpre) + intra-chunk causal part
    float outacc[16], den[16];
#pragma unroll
    for (int r = 0; r < 16; ++r) { outacc[r] = 0.f; den[r] = 0.f; }
    const float* sp = Spre + ((size_t)bh * NCH + c) * (HD * HD);
    for (int d = 0; d < HD; ++d) {
        float spv = sp[d * HD + e];
        float zv = zs[d];
#pragma unroll
        for (int r = 0; r < 16; ++r) {
            float qv = Qs[4 * r + g4][d];
            outacc[r] += qv * spv;
            den[r]    += qv * zv;
        }
    }
    for (int u = 0; u < CHK; ++u) {
        float vv = Vs[u][e];
#pragma unroll
        for (int r = 0; r < 16; ++r) {
            int t = 4 * r + g4;
            if (u <= t) {
                float a = Asc[t * CHK + u];
                outacc[r] += a * vv;
                den[r]    += a;
            }
        }
    }
#pragma unroll
    for (int r = 0; r < 16; ++r) {
        int t = 4 * r + g4;
        out[rowbase + (size_t)t * DM + e] = outacc[r] / (den[r] + 1e-6f);
    }
}

// LayerNorm row-wise over 512, fp32 in/out
__global__ __launch_bounds__(256) void ln_kernel(
    const float* __restrict__ in, const float* __restrict__ gg,
    const float* __restrict__ bb, float* __restrict__ out)
{
    __shared__ float red[8];
    int row = blockIdx.x, tid = threadIdx.x;
    const float* xp = in + (size_t)row * DM;
    float2 xv = *(const float2*)(xp + 2 * tid);
    float s = xv.x + xv.y;
    float sq = xv.x * xv.x + xv.y * xv.y;
#pragma unroll
    for (int off = 32; off > 0; off >>= 1) {
        s  += __shfl_down(s, off);
        sq += __shfl_down(sq, off);
    }
    if ((tid & 63) == 0) { red[tid >> 6] = s; red[4 + (tid >> 6)] = sq; }
    __syncthreads();
    float st = red[0] + red[1] + red[2] + red[3];
    float sqt = red[4] + red[5] + red[6] + red[7];
    float m = st * (1.0f / DM);
    float var = sqt * (1.0f / DM) - m * m;
    float rs = rsqrtf(var + 1e-5f);
    float2 o;
    o.x = (xv.x - m) * rs * gg[2 * tid]     + bb[2 * tid];
    o.y = (xv.y - m) * rs * gg[2 * tid + 1] + bb[2 * tid + 1];
    *(float2*)(out + (size_t)row * DM + 2 * tid) = o;
}

extern "C" void kernel_launch(void* const* d_in, const int* in_sizes, int n_in,
                              void* d_out, int out_size, void* d_ws, size_t ws_size,
                              hipStream_t stream)
{
    (void)in_sizes; (void)n_in; (void)out_size; (void)ws_size;
    const int*   x    = (const int*)d_in[0];
    const float* emb  = (const float*)d_in[1];
    const float* Wqkv = (const float*)d_in[2];
    const float* bqkv = (const float*)d_in[3];
    const float* Wo   = (const float*)d_in[4];
    const float* bo   = (const float*)d_in[5];
    const float* ln1g = (const float*)d_in[6];
    const float* ln1b = (const float*)d_in[7];
    const float* W1   = (const float*)d_in[8];
    const float* b1   = (const float*)d_in[9];
    const float* W2   = (const float*)d_in[10];
    const float* b2   = (const float*)d_in[11];
    const float* ln2g = (const float*)d_in[12];
    const float* ln2b = (const float*)d_in[13];
    const float* lnfg = (const float*)d_in[14];
    const float* lnfb = (const float*)d_in[15];
    const float* Wout = (const float*)d_in[16];
    const float* bout = (const float*)d_in[17];

    float* h    = (float*)d_ws;                          // [MR, DM]
    float* h2   = h    + (size_t)MR * DM;                // [MR, DM]
    float* qb   = h2   + (size_t)MR * DM;                // [MR, DM]
    float* kb   = qb   + (size_t)MR * DM;                // [MR, DM]
    float* vb   = kb   + (size_t)MR * DM;                // [MR, DM]
    float* ab   = vb   + (size_t)MR * DM;                // [MR, DM] attention out
    float* mid  = ab   + (size_t)MR * DM;                // [MR, DFF]
    float* Ssum = mid  + (size_t)MR * DFF;               // [NBH, NCH, 64, 64]
    float* Spre = Ssum + (size_t)NBH * NCH * HD * HD;    // [NBH, NCH, 64, 64]
    float* zsum = Spre + (size_t)NBH * NCH * HD * HD;    // [NBH, NCH, 64]
    float* zpre = zsum + (size_t)NBH * NCH * HD;         // [NBH, NCH, 64]

    embed_kernel<<<MR, 256, 0, stream>>>(x, emb, h);

    for (int l = 0; l < NL; ++l) {
        const float* Wq = Wqkv + ((size_t)l * 3 + 0) * DM * DM;
        const float* Wk = Wqkv + ((size_t)l * 3 + 1) * DM * DM;
        const float* Wv = Wqkv + ((size_t)l * 3 + 2) * DM * DM;
        const float* bq = bqkv + ((size_t)l * 3 + 0) * DM;
        const float* bk = bqkv + ((size_t)l * 3 + 1) * DM;
        const float* bv = bqkv + ((size_t)l * 3 + 2) * DM;

        gemm_kernel<<<dim3(MR / 64, DM / 64), 256, 0, stream>>>(h, Wq, bq, nullptr, qb, DM, DM, 0);
        gemm_kernel<<<dim3(MR / 64, DM / 64), 256, 0, stream>>>(h, Wk, bk, nullptr, kb, DM, DM, 0);
        gemm_kernel<<<dim3(MR / 64, DM / 64), 256, 0, stream>>>(h, Wv, bv, nullptr, vb, DM, DM, 0);

        feat_kernel<<<(MR * DM) / 256, 256, 0, stream>>>(qb, kb);
        chunksum_kernel<<<NBH * NCH, 256, 0, stream>>>(kb, vb, Ssum, zsum);
        prefix_kernel<<<NBH * 16, 256, 0, stream>>>(Ssum, Spre, zsum, zpre);
        attn_kernel<<<NBH * NCH, 256, 0, stream>>>(qb, kb, vb, Spre, zpre, ab);

        gemm_kernel<<<dim3(MR / 64, DM / 64), 256, 0, stream>>>(
            ab, Wo + (size_t)l * DM * DM, bo + (size_t)l * DM, h, h2, DM, DM, 0);
        ln_kernel<<<MR, 256, 0, stream>>>(h2, ln1g + (size_t)l * DM, ln1b + (size_t)l * DM, h);

        gemm_kernel<<<dim3(MR / 64, DFF / 64), 256, 0, stream>>>(
            h, W1 + (size_t)l * DM * DFF, b1 + (size_t)l * DFF, nullptr, mid, DFF, DM, 1);
        gemm_kernel<<<dim3(MR / 64, DM / 64), 256, 0, stream>>>(
            mid, W2 + (size_t)l * DFF * DM, b2 + (size_t)l * DM, h, h2, DM, DFF, 0);
        ln_kernel<<<MR, 256, 0, stream>>>(h2, ln2g + (size_t)l * DM, ln2b + (size_t)l * DM, h);
    }

    ln_kernel<<<MR, 256, 0, stream>>>(h, lnfg, lnfb, h2);
    gemm_kernel<<<dim3(MR / 64, (NT + 63) / 64), 256, 0, stream>>>(
        h2, Wout, bout, nullptr, (float*)d_out, NT, DM, 0);
}

// Round 3
// 4442.609 us; speedup vs baseline: 2.5966x; 2.5966x over previous
//
#include <hip/hip_runtime.h>
#include <hip/hip_bf16.h>

#define DM 512
#define DFF 2048
#define NB 4
#define SEQ 2048
#define NH 8
#define HD 64
#define NL 12
#define NT 400
#define MR (NB*SEQ)      // 8192 rows
#define CHK 64           // attention chunk length
#define NCH (SEQ/CHK)    // 32 chunks
#define NBH (NB*NH)      // 32 (b,h) pairs
#define QS  (3*DM)       // fused qkv row stride = 1536

typedef unsigned short u16;
typedef short bfrag __attribute__((ext_vector_type(8)));   // 8 bf16 (4 VGPRs)
typedef float ffrag __attribute__((ext_vector_type(4)));   // 4 fp32 acc

__device__ __forceinline__ float bf2f(u16 u) { return __uint_as_float(((unsigned)u) << 16); }
__device__ __forceinline__ u16 f2bf(float f) {
    unsigned u = __float_as_uint(f);
    u += 0x7fffu + ((u >> 16) & 1u);   // round-to-nearest-even
    return (u16)(u >> 16);
}

__device__ __forceinline__ void gload_lds16(const u16* g, u16* l) {
    __builtin_amdgcn_global_load_lds((const __attribute__((address_space(1))) void*)g,
                                     (__attribute__((address_space(3))) void*)l, 16, 0, 0);
}

// ---------------- weight transpose+convert: in[mi][K][N] fp32 -> out[mi][Nout][K] bf16
__global__ __launch_bounds__(256) void wtr_kernel(const float* __restrict__ in,
                                                  u16* __restrict__ out,
                                                  int K, int N, int Nout)
{
    __shared__ float T[64][65];
    int n0 = blockIdx.x << 6, k0 = blockIdx.y << 6;
    const float* ip = in + (size_t)blockIdx.z * K * N;
    u16* op = out + (size_t)blockIdx.z * Nout * K;
    int c = threadIdx.x & 63, r = threadIdx.x >> 6;
#pragma unroll
    for (int i = 0; i < 16; ++i) {
        int k = k0 + 4 * i + r;
        int n = n0 + c;
        T[4 * i + r][c] = (n < N) ? ip[(size_t)k * N + n] : 0.f;
    }
    __syncthreads();
#pragma unroll
    for (int i = 0; i < 16; ++i) {
        int n = n0 + 4 * i + r;
        op[(size_t)n * K + k0 + c] = f2bf(T[c][4 * i + r]);
    }
}

// ---------------- embed: h fp32 + hb bf16
__global__ __launch_bounds__(256) void embed_kernel(const int* __restrict__ x,
                                                    const float* __restrict__ emb,
                                                    float* __restrict__ h,
                                                    u16* __restrict__ hb)
{
    int row = blockIdx.x;
    int s = row & (SEQ - 1);
    int tok = x[row];
    int j = threadIdx.x;
    float2 ev = *(const float2*)(emb + (size_t)tok * DM + 2 * j);
    const float scale = 22.627416997969522f;           // sqrt(512)
    float dv = expf((float)(2 * j) * (-9.210340371976184f / 512.0f));
    float ang = (float)s * dv;
    float2 o;
    o.x = ev.x * scale + sinf(ang);
    o.y = ev.y * scale + cosf(ang);
    *(float2*)(h + (size_t)row * DM + 2 * j) = o;
    ushort2 ob; ob.x = f2bf(o.x); ob.y = f2bf(o.y);
    *(ushort2*)(hb + (size_t)row * DM + 2 * j) = ob;
}

// ---------------- MFMA GEMM: C[M,N] = A[M,K](bf16) @ Bt[N,K]^T(bf16) + bias
// 128x128 tile, 256 thr (4 waves 2x2), K-step 32, global_load_lds width 16.
// Epilogue: +bias, +res(fp32), relu, elu+1 on cols<elu_cols; write Cf fp32 / Cb bf16 (stride ldc).
__global__ __launch_bounds__(256) void mfma_gemm(
    const u16* __restrict__ A, const u16* __restrict__ Bt,
    const float* __restrict__ bias, const float* __restrict__ res,
    float* __restrict__ Cf, u16* __restrict__ Cb,
    int N, int K, int ldc, int Nw, int relu, int elu_cols)
{
    __shared__ __align__(16) u16 As[128 * 32];
    __shared__ __align__(16) u16 Bs[128 * 32];
    const int tid = threadIdx.x;
    const int w = tid >> 6, lane = tid & 63;
    const int m0 = blockIdx.x << 7, n0 = blockIdx.y << 7;
    const int wm = ((w >> 1) << 6), wn = ((w & 1) << 6);
    const int row16 = lane & 15, kq = lane >> 4;
    const int srow = lane >> 2;          // 0..15 within 16-row chunk
    const int skoff = (lane & 3) << 3;   // 0,8,16,24 (bf16 elems)

    ffrag acc[4][4] = {};

    for (int k0 = 0; k0 < K; k0 += 32) {
#pragma unroll
        for (int q = 0; q < 2; ++q) {
            int ci = w + (q << 2);                    // 0..7
            int mrow = (ci << 4) + srow;              // 0..127
            gload_lds16(A  + (size_t)(m0 + mrow) * K + k0 + skoff, As + (ci << 9));
            gload_lds16(Bt + (size_t)(n0 + mrow) * K + k0 + skoff, Bs + (ci << 9));
        }
        __syncthreads();
        bfrag af[4], bfq[4];
#pragma unroll
        for (int i = 0; i < 4; ++i) {
            af[i]  = *(const bfrag*)(As + ((wm + (i << 4) + row16) << 5) + (kq << 3));
            bfq[i] = *(const bfrag*)(Bs + ((wn + (i << 4) + row16) << 5) + (kq << 3));
        }
#pragma unroll
        for (int i = 0; i < 4; ++i)
#pragma unroll
            for (int j = 0; j < 4; ++j)
                acc[i][j] = __builtin_amdgcn_mfma_f32_16x16x32_bf16(af[i], bfq[j], acc[i][j], 0, 0, 0);
        __syncthreads();
    }

    const int crow = (lane >> 4) << 2;   // C/D: row=(lane>>4)*4+r, col=lane&15
    const int ccol = lane & 15;
#pragma unroll
    for (int i = 0; i < 4; ++i) {
        int mg = m0 + wm + (i << 4) + crow;
#pragma unroll
        for (int j = 0; j < 4; ++j) {
            int ng = n0 + wn + (j << 4) + ccol;
            if (ng < Nw) {
                float bsv = bias[ng];
#pragma unroll
                for (int r = 0; r < 4; ++r) {
                    float v = acc[i][j][r] + bsv;
                    size_t idx = (size_t)(mg + r) * ldc + ng;
                    if (res) v += res[idx];
                    if (relu) v = fmaxf(v, 0.f);
                    if (ng < elu_cols) v = (v > 0.f) ? v + 1.f : __expf(v);
                    if (Cf) Cf[idx] = v;
                    if (Cb) Cb[idx] = f2bf(v);
                }
            }
        }
    }
}

// ---------------- per (b,h,chunk): Ssum[d][e] = sum_t k[t][d]*v[t][e]; zsum[d]=sum_t k[t][d]
__global__ __launch_bounds__(256) void chunksum_kernel(
    const u16* __restrict__ qkv, float* __restrict__ Ssum, float* __restrict__ zsum)
{
    __shared__ float Ks[CHK][HD + 1];
    __shared__ float Vs[CHK][HD + 1];
    int blk = blockIdx.x;
    int c = blk % NCH; int bh = blk / NCH;
    int hh = bh % NH;  int b = bh / NH;
    const u16* kbase = qkv + ((size_t)b * SEQ + (size_t)c * CHK) * QS + DM + hh * HD;
    const u16* vbase = kbase + DM;
    int tid = threadIdx.x;
    int e = tid & 63, g4 = tid >> 6;
#pragma unroll
    for (int i = 0; i < 16; ++i) {
        int t = g4 + 4 * i;
        Ks[t][e] = bf2f(kbase[(size_t)t * QS + e]);
        Vs[t][e] = bf2f(vbase[(size_t)t * QS + e]);
    }
    __syncthreads();
    float sacc[16];
#pragma unroll
    for (int i = 0; i < 16; ++i) sacc[i] = 0.f;
    for (int t = 0; t < CHK; ++t) {
        float vv = Vs[t][e];
#pragma unroll
        for (int i = 0; i < 16; ++i) sacc[i] += Ks[t][g4 + 4 * i] * vv;
    }
    float* So = Ssum + (size_t)blk * (HD * HD);
#pragma unroll
    for (int i = 0; i < 16; ++i) So[(g4 + 4 * i) * HD + e] = sacc[i];
    if (tid < 64) {
        float z = 0.f;
        for (int t = 0; t < CHK; ++t) z += Ks[t][tid];
        zsum[(size_t)blk * HD + tid] = z;
    }
}

// ---------------- exclusive prefix over chunks, IN PLACE on Ssum / zsum
__global__ __launch_bounds__(256) void prefix_kernel(float* __restrict__ Ssum,
                                                     float* __restrict__ zsum)
{
    int bh = blockIdx.x >> 4;
    int eg = blockIdx.x & 15;
    int entry = (eg << 8) + threadIdx.x;     // 0..4095
    size_t base = (size_t)bh * NCH * (HD * HD) + entry;
    float pre = 0.f;
    for (int c = 0; c < NCH; ++c) {
        float cur = Ssum[base + (size_t)c * (HD * HD)];
        Ssum[base + (size_t)c * (HD * HD)] = pre;
        pre += cur;
    }
    if (eg == 0 && threadIdx.x < 64) {
        size_t zb = (size_t)bh * NCH * HD + threadIdx.x;
        float zp = 0.f;
        for (int c = 0; c < NCH; ++c) {
            float cur = zsum[zb + c * HD];
            zsum[zb + c * HD] = zp;
            zp += cur;
        }
    }
}

// ---------------- per (b,h,chunk) attention; Spre/zpre are the prefixed Ssum/zsum
__global__ __launch_bounds__(256) void attn_kernel(
    const u16* __restrict__ qkv, const float* __restrict__ Spre,
    const float* __restrict__ zpre, u16* __restrict__ ab)
{
    __shared__ float Qs[CHK][HD + 1];
    __shared__ float Ks[CHK][HD + 1];   // reused for 64x64 scores after phase A
    __shared__ float Vs[CHK][HD + 1];
    __shared__ float zs[HD];
    float* Asc = &Ks[0][0];
    int blk = blockIdx.x;
    int c = blk % NCH; int bh = blk / NCH;
    int hh = bh % NH;  int b = bh / NH;
    int tid = threadIdx.x;
    const u16* qbase = qkv + ((size_t)b * SEQ + (size_t)c * CHK) * QS + hh * HD;
    int e = tid & 63, g4 = tid >> 6;
#pragma unroll
    for (int i = 0; i < 16; ++i) {
        int t = g4 + 4 * i;
        Qs[t][e] = bf2f(qbase[(size_t)t * QS + e]);
        Ks[t][e] = bf2f(qbase[(size_t)t * QS + DM + e]);
        Vs[t][e] = bf2f(qbase[(size_t)t * QS + 2 * DM + e]);
    }
    if (tid < 64) zs[tid] = zpre[((size_t)bh * NCH + c) * HD + tid];
    __syncthreads();
    float sdot[16];
#pragma unroll
    for (int i = 0; i < 16; ++i) {
        int t = 4 * i + g4;
        float sd = 0.f;
#pragma unroll
        for (int d = 0; d < HD; ++d) sd += Qs[t][d] * Ks[e][d];
        sdot[i] = sd;
    }
    __syncthreads();
#pragma unroll
    for (int i = 0; i < 16; ++i) Asc[(4 * i + g4) * CHK + e] = sdot[i];
    __syncthreads();
    float outacc[16], den[16];
#pragma unroll
    for (int r = 0; r < 16; ++r) { outacc[r] = 0.f; den[r] = 0.f; }
    const float* sp = Spre + ((size_t)bh * NCH + c) * (HD * HD);
    for (int d = 0; d < HD; ++d) {
        float spv = sp[d * HD + e];
        float zv = zs[d];
#pragma unroll
        for (int r = 0; r < 16; ++r) {
            float qv = Qs[4 * r + g4][d];
            outacc[r] += qv * spv;
            den[r]    += qv * zv;
        }
    }
    for (int u = 0; u < CHK; ++u) {
        float vv = Vs[u][e];
#pragma unroll
        for (int r = 0; r < 16; ++r) {
            int t = 4 * r + g4;
            if (u <= t) {
                float a = Asc[t * CHK + u];
                outacc[r] += a * vv;
                den[r]    += a;
            }
        }
    }
#pragma unroll
    for (int r = 0; r < 16; ++r) {
        int t = 4 * r + g4;
        ab[((size_t)b * SEQ + (size_t)c * CHK + t) * DM + hh * HD + e] =
            f2bf(outacc[r] / (den[r] + 1e-6f));
    }
}

// ---------------- LayerNorm (in-place capable): fp32 out + bf16 copy
__global__ __launch_bounds__(256) void ln_kernel(
    const float* __restrict__ in, const float* __restrict__ gg,
    const float* __restrict__ bb, float* __restrict__ out, u16* __restrict__ outb)
{
    __shared__ float red[8];
    int row = blockIdx.x, tid = threadIdx.x;
    const float* xp = in + (size_t)row * DM;
    float2 xv = *(const float2*)(xp + 2 * tid);
    float s = xv.x + xv.y;
    float sq = xv.x * xv.x + xv.y * xv.y;
#pragma unroll
    for (int off = 32; off > 0; off >>= 1) {
        s  += __shfl_down(s, off);
        sq += __shfl_down(sq, off);
    }
    if ((tid & 63) == 0) { red[tid >> 6] = s; red[4 + (tid >> 6)] = sq; }
    __syncthreads();
    float st = red[0] + red[1] + red[2] + red[3];
    float sqt = red[4] + red[5] + red[6] + red[7];
    float m = st * (1.0f / DM);
    float var = sqt * (1.0f / DM) - m * m;
    float rs = rsqrtf(var + 1e-5f);
    float2 o;
    o.x = (xv.x - m) * rs * gg[2 * tid]     + bb[2 * tid];
    o.y = (xv.y - m) * rs * gg[2 * tid + 1] + bb[2 * tid + 1];
    *(float2*)(out + (size_t)row * DM + 2 * tid) = o;
    ushort2 ob; ob.x = f2bf(o.x); ob.y = f2bf(o.y);
    *(ushort2*)(outb + (size_t)row * DM + 2 * tid) = ob;
}

extern "C" void kernel_launch(void* const* d_in, const int* in_sizes, int n_in,
                              void* d_out, int out_size, void* d_ws, size_t ws_size,
                              hipStream_t stream)
{
    (void)in_sizes; (void)n_in; (void)out_size; (void)ws_size;
    const int*   x    = (const int*)d_in[0];
    const float* emb  = (const float*)d_in[1];
    const float* Wqkv = (const float*)d_in[2];
    const float* bqkv = (const float*)d_in[3];
    const float* Wo   = (const float*)d_in[4];
    const float* bo   = (const float*)d_in[5];
    const float* ln1g = (const float*)d_in[6];
    const float* ln1b = (const float*)d_in[7];
    const float* W1   = (const float*)d_in[8];
    const float* b1   = (const float*)d_in[9];
    const float* W2   = (const float*)d_in[10];
    const float* b2   = (const float*)d_in[11];
    const float* ln2g = (const float*)d_in[12];
    const float* ln2b = (const float*)d_in[13];
    const float* lnfg = (const float*)d_in[14];
    const float* lnfb = (const float*)d_in[15];
    const float* Wout = (const float*)d_in[16];
    const float* bout = (const float*)d_in[17];

    char* p = (char*)d_ws;
    float* h     = (float*)p;  p += (size_t)MR * DM * 4;       // fp32 residual stream
    u16*  hb     = (u16*)p;    p += (size_t)MR * DM * 2;       // bf16 copy of h
    u16*  qkvb   = (u16*)p;    p += (size_t)MR * QS * 2;       // fused q|k|v bf16
    u16*  abb    = (u16*)p;    p += (size_t)MR * DM * 2;       // attn out bf16
    u16*  midb   = (u16*)p;    p += (size_t)MR * DFF * 2;      // relu(ff1) bf16
    float* Ssum  = (float*)p;  p += (size_t)NBH * NCH * HD * HD * 4;
    float* zsum  = (float*)p;  p += (size_t)NBH * NCH * HD * 4;
    u16* WqkvT   = (u16*)p;    p += (size_t)NL * 3 * DM * DM * 2;  // [l][1536][512]
    u16* WoT     = (u16*)p;    p += (size_t)NL * DM * DM * 2;      // [l][512][512]
    u16* W1T     = (u16*)p;    p += (size_t)NL * DFF * DM * 2;     // [l][2048][512]
    u16* W2T     = (u16*)p;    p += (size_t)NL * DM * DFF * 2;     // [l][512][2048]
    u16* WoutT   = (u16*)p;    p += (size_t)DM * DM * 2;           // [512pad][512]

    // ---- weight prep (every call; ws is re-poisoned)
    wtr_kernel<<<dim3(8, 8, NL * 3), 256, 0, stream>>>(Wqkv, WqkvT, DM, DM, DM);
    wtr_kernel<<<dim3(8, 8, NL), 256, 0, stream>>>(Wo, WoT, DM, DM, DM);
    wtr_kernel<<<dim3(32, 8, NL), 256, 0, stream>>>(W1, W1T, DM, DFF, DFF);
    wtr_kernel<<<dim3(8, 32, NL), 256, 0, stream>>>(W2, W2T, DFF, DM, DM);
    wtr_kernel<<<dim3(8, 8, 1), 256, 0, stream>>>(Wout, WoutT, DM, NT, DM);

    embed_kernel<<<MR, 256, 0, stream>>>(x, emb, h, hb);

    for (int l = 0; l < NL; ++l) {
        // fused QKV + bias + elu(q,k)+1, bf16 out [MR][1536]
        mfma_gemm<<<dim3(MR / 128, QS / 128), 256, 0, stream>>>(
            hb, WqkvT + (size_t)l * QS * DM, bqkv + (size_t)l * QS, nullptr,
            nullptr, qkvb, QS, DM, QS, QS, 0, 2 * DM);

        chunksum_kernel<<<NBH * NCH, 256, 0, stream>>>(qkvb, Ssum, zsum);
        prefix_kernel<<<NBH * 16, 256, 0, stream>>>(Ssum, zsum);
        attn_kernel<<<NBH * NCH, 256, 0, stream>>>(qkvb, Ssum, zsum, abb);

        // h += attn @ Wo + bo  (in-place residual)
        mfma_gemm<<<dim3(MR / 128, DM / 128), 256, 0, stream>>>(
            abb, WoT + (size_t)l * DM * DM, bo + (size_t)l * DM, h,
            h, nullptr, DM, DM, DM, DM, 0, 0);
        ln_kernel<<<MR, 256, 0, stream>>>(h, ln1g + (size_t)l * DM, ln1b + (size_t)l * DM, h, hb);

        // mid = relu(h @ W1 + b1), bf16
        mfma_gemm<<<dim3(MR / 128, DFF / 128), 256, 0, stream>>>(
            hb, W1T + (size_t)l * DFF * DM, b1 + (size_t)l * DFF, nullptr,
            nullptr, midb, DFF, DM, DFF, DFF, 1, 0);
        // h += mid @ W2 + b2
        mfma_gemm<<<dim3(MR / 128, DM / 128), 256, 0, stream>>>(
            midb, W2T + (size_t)l * DM * DFF, b2 + (size_t)l * DM, h,
            h, nullptr, DM, DFF, DM, DM, 0, 0);
        ln_kernel<<<MR, 256, 0, stream>>>(h, ln2g + (size_t)l * DM, ln2b + (size_t)l * DM, h, hb);
    }

    ln_kernel<<<MR, 256, 0, stream>>>(h, lnfg, lnfb, h, hb);
    // logits = hb @ WoutT^T + bout  (N padded to 512, write 400)
    mfma_gemm<<<dim3(MR / 128, DM / 128), 256, 0, stream>>>(
        hb, WoutT, bout, nullptr, (float*)d_out, nullptr, DM, DM, NT, NT, 0, 0);
}

// Round 4
// 2892.110 us; speedup vs baseline: 3.9886x; 1.5361x over previous
//
#include <hip/hip_runtime.h>
#include <hip/hip_bf16.h>

#define DM 512
#define DFF 2048
#define NB 4
#define SEQ 2048
#define NH 8
#define HD 64
#define NL 12
#define NT 400
#define MR (NB*SEQ)      // 8192 rows
#define CHK 64           // attention chunk length
#define NCH (SEQ/CHK)    // 32 chunks
#define NBH (NB*NH)      // 32 (b,h) pairs
#define QS  (3*DM)       // fused qkv row stride = 1536
#define TP 72            // transposed-tile LDS stride (16B-aligned rows)

typedef unsigned short u16;
typedef short bfrag __attribute__((ext_vector_type(8)));   // 8 bf16 (4 VGPRs)
typedef float ffrag __attribute__((ext_vector_type(4)));   // 4 fp32 acc

__device__ __forceinline__ float bf2f(u16 u) { return __uint_as_float(((unsigned)u) << 16); }
__device__ __forceinline__ u16 f2bf(float f) {
    unsigned u = __float_as_uint(f);
    u += 0x7fffu + ((u >> 16) & 1u);   // round-to-nearest-even
    return (u16)(u >> 16);
}

__device__ __forceinline__ void gload_lds16(const u16* g, u16* l) {
    __builtin_amdgcn_global_load_lds((const __attribute__((address_space(1))) void*)g,
                                     (__attribute__((address_space(3))) void*)l, 16, 0, 0);
}

// ---------------- weight transpose+convert: in[mi][K][N] fp32 -> out[mi][Nout][K] bf16
__global__ __launch_bounds__(256) void wtr_kernel(const float* __restrict__ in,
                                                  u16* __restrict__ out,
                                                  int K, int N, int Nout)
{
    __shared__ float T[64][65];
    int n0 = blockIdx.x << 6, k0 = blockIdx.y << 6;
    const float* ip = in + (size_t)blockIdx.z * K * N;
    u16* op = out + (size_t)blockIdx.z * Nout * K;
    int c = threadIdx.x & 63, r = threadIdx.x >> 6;
#pragma unroll
    for (int i = 0; i < 16; ++i) {
        int k = k0 + 4 * i + r;
        int n = n0 + c;
        T[4 * i + r][c] = (n < N) ? ip[(size_t)k * N + n] : 0.f;
    }
    __syncthreads();
#pragma unroll
    for (int i = 0; i < 16; ++i) {
        int n = n0 + 4 * i + r;
        op[(size_t)n * K + k0 + c] = f2bf(T[c][4 * i + r]);
    }
}

// ---------------- embed: h fp32 + hb bf16
__global__ __launch_bounds__(256) void embed_kernel(const int* __restrict__ x,
                                                    const float* __restrict__ emb,
                                                    float* __restrict__ h,
                                                    u16* __restrict__ hb)
{
    int row = blockIdx.x;
    int s = row & (SEQ - 1);
    int tok = x[row];
    int j = threadIdx.x;
    float2 ev = *(const float2*)(emb + (size_t)tok * DM + 2 * j);
    const float scale = 22.627416997969522f;           // sqrt(512)
    float dv = expf((float)(2 * j) * (-9.210340371976184f / 512.0f));
    float ang = (float)s * dv;
    float2 o;
    o.x = ev.x * scale + sinf(ang);
    o.y = ev.y * scale + cosf(ang);
    *(float2*)(h + (size_t)row * DM + 2 * j) = o;
    ushort2 ob; ob.x = f2bf(o.x); ob.y = f2bf(o.y);
    *(ushort2*)(hb + (size_t)row * DM + 2 * j) = ob;
}

// ---------------- MFMA GEMM: C[M,N] = A[M,K](bf16) @ Bt[N,K]^T(bf16) + bias
__global__ __launch_bounds__(256) void mfma_gemm(
    const u16* __restrict__ A, const u16* __restrict__ Bt,
    const float* __restrict__ bias, const float* __restrict__ res,
    float* __restrict__ Cf, u16* __restrict__ Cb,
    int N, int K, int ldc, int Nw, int relu, int elu_cols)
{
    __shared__ __align__(16) u16 As[128 * 32];
    __shared__ __align__(16) u16 Bs[128 * 32];
    const int tid = threadIdx.x;
    const int w = tid >> 6, lane = tid & 63;
    const int m0 = blockIdx.x << 7, n0 = blockIdx.y << 7;
    const int wm = ((w >> 1) << 6), wn = ((w & 1) << 6);
    const int row16 = lane & 15, kq = lane >> 4;
    const int srow = lane >> 2;          // 0..15 within 16-row chunk
    const int skoff = (lane & 3) << 3;   // 0,8,16,24 (bf16 elems)

    ffrag acc[4][4] = {};

    for (int k0 = 0; k0 < K; k0 += 32) {
#pragma unroll
        for (int q = 0; q < 2; ++q) {
            int ci = w + (q << 2);                    // 0..7
            int mrow = (ci << 4) + srow;              // 0..127
            gload_lds16(A  + (size_t)(m0 + mrow) * K + k0 + skoff, As + (ci << 9));
            gload_lds16(Bt + (size_t)(n0 + mrow) * K + k0 + skoff, Bs + (ci << 9));
        }
        __syncthreads();
        bfrag af[4], bfq[4];
#pragma unroll
        for (int i = 0; i < 4; ++i) {
            af[i]  = *(const bfrag*)(As + ((wm + (i << 4) + row16) << 5) + (kq << 3));
            bfq[i] = *(const bfrag*)(Bs + ((wn + (i << 4) + row16) << 5) + (kq << 3));
        }
#pragma unroll
        for (int i = 0; i < 4; ++i)
#pragma unroll
            for (int j = 0; j < 4; ++j)
                acc[i][j] = __builtin_amdgcn_mfma_f32_16x16x32_bf16(af[i], bfq[j], acc[i][j], 0, 0, 0);
        __syncthreads();
    }

    const int crow = (lane >> 4) << 2;   // C/D: row=(lane>>4)*4+r, col=lane&15
    const int ccol = lane & 15;
#pragma unroll
    for (int i = 0; i < 4; ++i) {
        int mg = m0 + wm + (i << 4) + crow;
#pragma unroll
        for (int j = 0; j < 4; ++j) {
            int ng = n0 + wn + (j << 4) + ccol;
            if (ng < Nw) {
                float bsv = bias[ng];
#pragma unroll
                for (int r = 0; r < 4; ++r) {
                    float v = acc[i][j][r] + bsv;
                    size_t idx = (size_t)(mg + r) * ldc + ng;
                    if (res) v += res[idx];
                    if (relu) v = fmaxf(v, 0.f);
                    if (ng < elu_cols) v = (v > 0.f) ? v + 1.f : __expf(v);
                    if (Cf) Cf[idx] = v;
                    if (Cb) Cb[idx] = f2bf(v);
                }
            }
        }
    }
}

// ---------------- chunksum (MFMA): Ssum[d][e] = sum_t K[t][d]*V[t][e]; zsum[d] = sum_t K[t][d]
__global__ __launch_bounds__(256) void chunksum_kernel(
    const u16* __restrict__ qkv, float* __restrict__ Ssum, float* __restrict__ zsum)
{
    __shared__ __align__(16) u16 KT[64 * TP];   // K^T: KT[d][t]
    __shared__ __align__(16) u16 VT[64 * TP];   // V^T: VT[e][t]
    int blk = blockIdx.x;
    int c = blk % NCH; int bh = blk / NCH;
    int hh = bh % NH;  int b = bh / NH;
    const u16* kbase = qkv + ((size_t)b * SEQ + (size_t)c * CHK) * QS + DM + hh * HD;
    const u16* vbase = kbase + DM;
    const int tid = threadIdx.x;
    const int w = tid >> 6, lane = tid & 63;
    const int col = lane & 15, quad = lane >> 4;

    {   // transpose-stage K and V
        int t = tid >> 2, d0 = (tid & 3) << 4;
        bfrag k0 = *(const bfrag*)(kbase + (size_t)t * QS + d0);
        bfrag k1 = *(const bfrag*)(kbase + (size_t)t * QS + d0 + 8);
        bfrag v0 = *(const bfrag*)(vbase + (size_t)t * QS + d0);
        bfrag v1 = *(const bfrag*)(vbase + (size_t)t * QS + d0 + 8);
#pragma unroll
        for (int i = 0; i < 8; ++i) {
            KT[(d0 + i) * TP + t] = (u16)k0[i];
            KT[(d0 + 8 + i) * TP + t] = (u16)k1[i];
            VT[(d0 + i) * TP + t] = (u16)v0[i];
            VT[(d0 + 8 + i) * TP + t] = (u16)v1[i];
        }
    }
    __syncthreads();

    bfrag ktf[2];
#pragma unroll
    for (int kk = 0; kk < 2; ++kk)
        ktf[kk] = *(const bfrag*)(KT + ((w << 4) + col) * TP + kk * 32 + (quad << 3));
    bfrag ones;
#pragma unroll
    for (int i = 0; i < 8; ++i) ones[i] = (short)0x3F80;

    ffrag acc[4] = {};
    ffrag zacc = {};
#pragma unroll
    for (int j = 0; j < 4; ++j)
#pragma unroll
        for (int kk = 0; kk < 2; ++kk) {
            bfrag vf = *(const bfrag*)(VT + ((j << 4) + col) * TP + kk * 32 + (quad << 3));
            acc[j] = __builtin_amdgcn_mfma_f32_16x16x32_bf16(ktf[kk], vf, acc[j], 0, 0, 0);
        }
    zacc = __builtin_amdgcn_mfma_f32_16x16x32_bf16(ktf[0], ones, zacc, 0, 0, 0);
    zacc = __builtin_amdgcn_mfma_f32_16x16x32_bf16(ktf[1], ones, zacc, 0, 0, 0);

    float* So = Ssum + (size_t)blk * (HD * HD);
#pragma unroll
    for (int j = 0; j < 4; ++j)
#pragma unroll
        for (int r = 0; r < 4; ++r)
            So[((w << 4) + (quad << 2) + r) * HD + (j << 4) + col] = acc[j][r];
    if (col == 0) {
#pragma unroll
        for (int r = 0; r < 4; ++r)
            zsum[(size_t)blk * HD + (w << 4) + (quad << 2) + r] = zacc[r];
    }
}

// ---------------- exclusive prefix over chunks, IN PLACE on Ssum / zsum
__global__ __launch_bounds__(256) void prefix_kernel(float* __restrict__ Ssum,
                                                     float* __restrict__ zsum)
{
    int bh = blockIdx.x >> 4;
    int eg = blockIdx.x & 15;
    int entry = (eg << 8) + threadIdx.x;     // 0..4095
    size_t base = (size_t)bh * NCH * (HD * HD) + entry;
    float pre = 0.f;
    for (int c = 0; c < NCH; ++c) {
        float cur = Ssum[base + (size_t)c * (HD * HD)];
        Ssum[base + (size_t)c * (HD * HD)] = pre;
        pre += cur;
    }
    if (eg == 0 && threadIdx.x < 64) {
        size_t zb = (size_t)bh * NCH * HD + threadIdx.x;
        float zp = 0.f;
        for (int c = 0; c < NCH; ++c) {
            float cur = zsum[zb + c * HD];
            zsum[zb + c * HD] = zp;
            zp += cur;
        }
    }
}

// ---------------- attention (MFMA): out[t] = (Q@Spre + tril(QK^T)@V) / (Q.zpre + rowsum(tril(QK^T)) + eps)
__global__ __launch_bounds__(256) void attn_kernel(
    const u16* __restrict__ qkv, const float* __restrict__ Spre,
    const float* __restrict__ zpre, u16* __restrict__ ab)
{
    __shared__ __align__(16) u16 Qs[64 * 64];    // Q row-major (stride 64, global_load_lds)
    __shared__ __align__(16) u16 KP[64 * TP];    // phase A: K rows (stride 64); phase B: P rows (stride TP)
    __shared__ __align__(16) u16 VT[64 * TP];    // V^T
    __shared__ __align__(16) u16 SpT[64 * TP];   // Spre^T (bf16)
    __shared__ __align__(16) u16 zb[64];         // zpre bf16
    int blk = blockIdx.x;
    int c = blk % NCH; int bh = blk / NCH;
    int hh = bh % NH;  int b = bh / NH;
    const int tid = threadIdx.x;
    const int w = tid >> 6, lane = tid & 63;
    const int col = lane & 15, quad = lane >> 4;
    const size_t rowbase = ((size_t)b * SEQ + (size_t)c * CHK);
    const u16* qbase = qkv + rowbase * QS + hh * HD;
    const u16* vbase = qbase + 2 * DM;

    // stage Q, K via global_load_lds (rows contiguous, stride 64)
#pragma unroll
    for (int li = 0; li < 2; ++li) {
        int ld = (li << 2) + w;                  // 0..7
        int grow = (ld << 3) + (lane >> 3);      // 0..63
        int gcol = (lane & 7) << 3;
        gload_lds16(qbase + (size_t)grow * QS + gcol, Qs + (ld << 9));
        gload_lds16(qbase + DM + (size_t)grow * QS + gcol, KP + (ld << 9));
    }
    {   // transpose-stage V
        int t = tid >> 2, e0 = (tid & 3) << 4;
        bfrag v0 = *(const bfrag*)(vbase + (size_t)t * QS + e0);
        bfrag v1 = *(const bfrag*)(vbase + (size_t)t * QS + e0 + 8);
#pragma unroll
        for (int i = 0; i < 8; ++i) {
            VT[(e0 + i) * TP + t] = (u16)v0[i];
            VT[(e0 + 8 + i) * TP + t] = (u16)v1[i];
        }
    }
    {   // transpose-stage Spre (fp32 -> bf16)
        const float* sp = Spre + ((size_t)bh * NCH + c) * (HD * HD);
        int d = tid >> 2, e0 = (tid & 3) << 4;
#pragma unroll
        for (int g = 0; g < 4; ++g) {
            float4 f = *(const float4*)(sp + d * HD + e0 + (g << 2));
            SpT[(e0 + (g << 2) + 0) * TP + d] = f2bf(f.x);
            SpT[(e0 + (g << 2) + 1) * TP + d] = f2bf(f.y);
            SpT[(e0 + (g << 2) + 2) * TP + d] = f2bf(f.z);
            SpT[(e0 + (g << 2) + 3) * TP + d] = f2bf(f.w);
        }
    }
    if (tid < 64) zb[tid] = f2bf(zpre[((size_t)bh * NCH + c) * HD + tid]);
    __syncthreads();

    // Q A-frags for this wave's 16 rows (kept in regs for S, inter, den)
    bfrag qf[2];
#pragma unroll
    for (int kk = 0; kk < 2; ++kk)
        qf[kk] = *(const bfrag*)(Qs + ((w << 4) + col) * 64 + kk * 32 + (quad << 3));

    // Phase A: S tiles (rows 16w..16w+15, all 64 cols)
    ffrag S[4] = {};
#pragma unroll
    for (int j = 0; j < 4; ++j)
#pragma unroll
        for (int kk = 0; kk < 2; ++kk) {
            bfrag kf = *(const bfrag*)(KP + ((j << 4) + col) * 64 + kk * 32 + (quad << 3));
            S[j] = __builtin_amdgcn_mfma_f32_16x16x32_bf16(qf[kk], kf, S[j], 0, 0, 0);
        }
    __syncthreads();   // everyone done reading K; KP becomes P

    // mask, fp32 row-sums (pre-rounding), write P bf16
    float rs[4] = {0.f, 0.f, 0.f, 0.f};
#pragma unroll
    for (int j = 0; j < 4; ++j)
#pragma unroll
        for (int r = 0; r < 4; ++r) {
            int t = (w << 4) + (quad << 2) + r;
            int u = (j << 4) + col;
            float sv = (u <= t) ? S[j][r] : 0.f;
            rs[r] += sv;
            KP[t * TP + u] = f2bf(sv);
        }
#pragma unroll
    for (int r = 0; r < 4; ++r) {
        rs[r] += __shfl_xor(rs[r], 1);
        rs[r] += __shfl_xor(rs[r], 2);
        rs[r] += __shfl_xor(rs[r], 4);
        rs[r] += __shfl_xor(rs[r], 8);
    }

    // den: Q . zpre via column-broadcast z B-frag (C-layout rows align with O)
    ffrag dacc = {};
#pragma unroll
    for (int kk = 0; kk < 2; ++kk) {
        bfrag zf = *(const bfrag*)(zb + kk * 32 + (quad << 3));
        dacc = __builtin_amdgcn_mfma_f32_16x16x32_bf16(qf[kk], zf, dacc, 0, 0, 0);
    }

    // Phase B: O = Q @ SpreT + P @ V  (wave reads only its own P rows; DS ops in-wave are ordered)
    ffrag O[4] = {};
    bfrag pf[2];
#pragma unroll
    for (int kk = 0; kk < 2; ++kk)
        pf[kk] = *(const bfrag*)(KP + ((w << 4) + col) * TP + kk * 32 + (quad << 3));
#pragma unroll
    for (int j = 0; j < 4; ++j)
#pragma unroll
        for (int kk = 0; kk < 2; ++kk) {
            bfrag sf = *(const bfrag*)(SpT + ((j << 4) + col) * TP + kk * 32 + (quad << 3));
            O[j] = __builtin_amdgcn_mfma_f32_16x16x32_bf16(qf[kk], sf, O[j], 0, 0, 0);
            bfrag vf = *(const bfrag*)(VT + ((j << 4) + col) * TP + kk * 32 + (quad << 3));
            O[j] = __builtin_amdgcn_mfma_f32_16x16x32_bf16(pf[kk], vf, O[j], 0, 0, 0);
        }

    // epilogue
#pragma unroll
    for (int j = 0; j < 4; ++j)
#pragma unroll
        for (int r = 0; r < 4; ++r) {
            int t = (w << 4) + (quad << 2) + r;
            int e = (j << 4) + col;
            float den = dacc[r] + rs[r] + 1e-6f;
            ab[(rowbase + t) * DM + hh * HD + e] = f2bf(O[j][r] / den);
        }
}

// ---------------- LayerNorm (in-place capable): fp32 out + bf16 copy
__global__ __launch_bounds__(256) void ln_kernel(
    const float* __restrict__ in, const float* __restrict__ gg,
    const float* __restrict__ bb, float* __restrict__ out, u16* __restrict__ outb)
{
    __shared__ float red[8];
    int row = blockIdx.x, tid = threadIdx.x;
    const float* xp = in + (size_t)row * DM;
    float2 xv = *(const float2*)(xp + 2 * tid);
    float s = xv.x + xv.y;
    float sq = xv.x * xv.x + xv.y * xv.y;
#pragma unroll
    for (int off = 32; off > 0; off >>= 1) {
        s  += __shfl_down(s, off);
        sq += __shfl_down(sq, off);
    }
    if ((tid & 63) == 0) { red[tid >> 6] = s; red[4 + (tid >> 6)] = sq; }
    __syncthreads();
    float st = red[0] + red[1] + red[2] + red[3];
    float sqt = red[4] + red[5] + red[6] + red[7];
    float m = st * (1.0f / DM);
    float var = sqt * (1.0f / DM) - m * m;
    float rs = rsqrtf(var + 1e-5f);
    float2 o;
    o.x = (xv.x - m) * rs * gg[2 * tid]     + bb[2 * tid];
    o.y = (xv.y - m) * rs * gg[2 * tid + 1] + bb[2 * tid + 1];
    *(float2*)(out + (size_t)row * DM + 2 * tid) = o;
    ushort2 ob; ob.x = f2bf(o.x); ob.y = f2bf(o.y);
    *(ushort2*)(outb + (size_t)row * DM + 2 * tid) = ob;
}

extern "C" void kernel_launch(void* const* d_in, const int* in_sizes, int n_in,
                              void* d_out, int out_size, void* d_ws, size_t ws_size,
                              hipStream_t stream)
{
    (void)in_sizes; (void)n_in; (void)out_size; (void)ws_size;
    const int*   x    = (const int*)d_in[0];
    const float* emb  = (const float*)d_in[1];
    const float* Wqkv = (const float*)d_in[2];
    const float* bqkv = (const float*)d_in[3];
    const float* Wo   = (const float*)d_in[4];
    const float* bo   = (const float*)d_in[5];
    const float* ln1g = (const float*)d_in[6];
    const float* ln1b = (const float*)d_in[7];
    const float* W1   = (const float*)d_in[8];
    const float* b1   = (const float*)d_in[9];
    const float* W2   = (const float*)d_in[10];
    const float* b2   = (const float*)d_in[11];
    const float* ln2g = (const float*)d_in[12];
    const float* ln2b = (const float*)d_in[13];
    const float* lnfg = (const float*)d_in[14];
    const float* lnfb = (const float*)d_in[15];
    const float* Wout = (const float*)d_in[16];
    const float* bout = (const float*)d_in[17];

    char* p = (char*)d_ws;
    float* h     = (float*)p;  p += (size_t)MR * DM * 4;       // fp32 residual stream
    u16*  hb     = (u16*)p;    p += (size_t)MR * DM * 2;       // bf16 copy of h
    u16*  qkvb   = (u16*)p;    p += (size_t)MR * QS * 2;       // fused q|k|v bf16
    u16*  abb    = (u16*)p;    p += (size_t)MR * DM * 2;       // attn out bf16
    u16*  midb   = (u16*)p;    p += (size_t)MR * DFF * 2;      // relu(ff1) bf16
    float* Ssum  = (float*)p;  p += (size_t)NBH * NCH * HD * HD * 4;
    float* zsum  = (float*)p;  p += (size_t)NBH * NCH * HD * 4;
    u16* WqkvT   = (u16*)p;    p += (size_t)NL * 3 * DM * DM * 2;  // [l][1536][512]
    u16* WoT     = (u16*)p;    p += (size_t)NL * DM * DM * 2;      // [l][512][512]
    u16* W1T     = (u16*)p;    p += (size_t)NL * DFF * DM * 2;     // [l][2048][512]
    u16* W2T     = (u16*)p;    p += (size_t)NL * DM * DFF * 2;     // [l][512][2048]
    u16* WoutT   = (u16*)p;    p += (size_t)DM * DM * 2;           // [512pad][512]

    // ---- weight prep (every call; ws is re-poisoned)
    wtr_kernel<<<dim3(8, 8, NL * 3), 256, 0, stream>>>(Wqkv, WqkvT, DM, DM, DM);
    wtr_kernel<<<dim3(8, 8, NL), 256, 0, stream>>>(Wo, WoT, DM, DM, DM);
    wtr_kernel<<<dim3(32, 8, NL), 256, 0, stream>>>(W1, W1T, DM, DFF, DFF);
    wtr_kernel<<<dim3(8, 32, NL), 256, 0, stream>>>(W2, W2T, DFF, DM, DM);
    wtr_kernel<<<dim3(8, 8, 1), 256, 0, stream>>>(Wout, WoutT, DM, NT, DM);

    embed_kernel<<<MR, 256, 0, stream>>>(x, emb, h, hb);

    for (int l = 0; l < NL; ++l) {
        // fused QKV + bias + elu(q,k)+1, bf16 out [MR][1536]
        mfma_gemm<<<dim3(MR / 128, QS / 128), 256, 0, stream>>>(
            hb, WqkvT + (size_t)l * QS * DM, bqkv + (size_t)l * QS, nullptr,
            nullptr, qkvb, QS, DM, QS, QS, 0, 2 * DM);

        chunksum_kernel<<<NBH * NCH, 256, 0, stream>>>(qkvb, Ssum, zsum);
        prefix_kernel<<<NBH * 16, 256, 0, stream>>>(Ssum, zsum);
        attn_kernel<<<NBH * NCH, 256, 0, stream>>>(qkvb, Ssum, zsum, abb);

        // h += attn @ Wo + bo  (in-place residual)
        mfma_gemm<<<dim3(MR / 128, DM / 128), 256, 0, stream>>>(
            abb, WoT + (size_t)l * DM * DM, bo + (size_t)l * DM, h,
            h, nullptr, DM, DM, DM, DM, 0, 0);
        ln_kernel<<<MR, 256, 0, stream>>>(h, ln1g + (size_t)l * DM, ln1b + (size_t)l * DM, h, hb);

        // mid = relu(h @ W1 + b1), bf16
        mfma_gemm<<<dim3(MR / 128, DFF / 128), 256, 0, stream>>>(
            hb, W1T + (size_t)l * DFF * DM, b1 + (size_t)l * DFF, nullptr,
            nullptr, midb, DFF, DM, DFF, DFF, 1, 0);
        // h += mid @ W2 + b2
        mfma_gemm<<<dim3(MR / 128, DM / 128), 256, 0, stream>>>(
            midb, W2T + (size_t)l * DM * DFF, b2 + (size_t)l * DM, h,
            h, nullptr, DM, DFF, DM, DM, 0, 0);
        ln_kernel<<<MR, 256, 0, stream>>>(h, ln2g + (size_t)l * DM, ln2b + (size_t)l * DM, h, hb);
    }

    ln_kernel<<<MR, 256, 0, stream>>>(h, lnfg, lnfb, h, hb);
    // logits = hb @ WoutT^T + bout  (N padded to 512, write 400)
    mfma_gemm<<<dim3(MR / 128, DM / 128), 256, 0, stream>>>(
        hb, WoutT, bout, nullptr, (float*)d_out, nullptr, DM, DM, NT, NT, 0, 0);
}

// Round 5
// 2469.266 us; speedup vs baseline: 4.6716x; 1.1712x over previous
//
#include <hip/hip_runtime.h>
#include <hip/hip_bf16.h>

#define DM 512
#define DFF 2048
#define NB 4
#define SEQ 2048
#define NH 8
#define HD 64
#define NL 12
#define NT 400
#define MR (NB*SEQ)      // 8192 rows
#define CHK 64           // attention chunk length
#define NCH (SEQ/CHK)    // 32 chunks
#define NBH (NB*NH)      // 32 (b,h) pairs
#define QS  (3*DM)       // fused qkv row stride = 1536
#define TP 72            // transposed-tile LDS stride (16B-aligned rows)

typedef unsigned short u16;
typedef short bfrag __attribute__((ext_vector_type(8)));   // 8 bf16 (4 VGPRs)
typedef float ffrag __attribute__((ext_vector_type(4)));   // 4 fp32 acc

__device__ __forceinline__ float bf2f(u16 u) { return __uint_as_float(((unsigned)u) << 16); }
__device__ __forceinline__ u16 f2bf(float f) {
    unsigned u = __float_as_uint(f);
    u += 0x7fffu + ((u >> 16) & 1u);   // round-to-nearest-even
    return (u16)(u >> 16);
}

__device__ __forceinline__ void gload_lds16(const u16* g, u16* l) {
    __builtin_amdgcn_global_load_lds((const __attribute__((address_space(1))) void*)g,
                                     (__attribute__((address_space(3))) void*)l, 16, 0, 0);
}

// ---------------- weight transpose+convert: in[mi][K][N] fp32 -> out[mi][Nout][K] bf16
__global__ __launch_bounds__(256) void wtr_kernel(const float* __restrict__ in,
                                                  u16* __restrict__ out,
                                                  int K, int N, int Nout)
{
    __shared__ float T[64][65];
    int n0 = blockIdx.x << 6, k0 = blockIdx.y << 6;
    const float* ip = in + (size_t)blockIdx.z * K * N;
    u16* op = out + (size_t)blockIdx.z * Nout * K;
    int c = threadIdx.x & 63, r = threadIdx.x >> 6;
#pragma unroll
    for (int i = 0; i < 16; ++i) {
        int k = k0 + 4 * i + r;
        int n = n0 + c;
        T[4 * i + r][c] = (n < N) ? ip[(size_t)k * N + n] : 0.f;
    }
    __syncthreads();
#pragma unroll
    for (int i = 0; i < 16; ++i) {
        int n = n0 + 4 * i + r;
        op[(size_t)n * K + k0 + c] = f2bf(T[c][4 * i + r]);
    }
}

// ---------------- embed: h fp32 + hb bf16
__global__ __launch_bounds__(256) void embed_kernel(const int* __restrict__ x,
                                                    const float* __restrict__ emb,
                                                    float* __restrict__ h,
                                                    u16* __restrict__ hb)
{
    int row = blockIdx.x;
    int s = row & (SEQ - 1);
    int tok = x[row];
    int j = threadIdx.x;
    float2 ev = *(const float2*)(emb + (size_t)tok * DM + 2 * j);
    const float scale = 22.627416997969522f;           // sqrt(512)
    float dv = expf((float)(2 * j) * (-9.210340371976184f / 512.0f));
    float ang = (float)s * dv;
    float2 o;
    o.x = ev.x * scale + sinf(ang);
    o.y = ev.y * scale + cosf(ang);
    *(float2*)(h + (size_t)row * DM + 2 * j) = o;
    ushort2 ob; ob.x = f2bf(o.x); ob.y = f2bf(o.y);
    *(ushort2*)(hb + (size_t)row * DM + 2 * j) = ob;
}

// ---------------- MFMA GEMM: C[M,N] = A[M,K](bf16) @ Bt[N,K]^T(bf16) + bias
// Tile BM x 128 (BM = 128 or 64), 256 thr (4 waves 2x2), K-step 32, global_load_lds width 16.
template<int BM>
__global__ __launch_bounds__(256) void mfma_gemm(
    const u16* __restrict__ A, const u16* __restrict__ Bt,
    const float* __restrict__ bias, const float* __restrict__ res,
    float* __restrict__ Cf, u16* __restrict__ Cb,
    int N, int K, int ldc, int Nw, int relu, int elu_cols)
{
    constexpr int ACH = BM / 16;          // A 16-row chunks
    constexpr int MI  = BM / 32;          // m-frags per wave
    __shared__ __align__(16) u16 As[BM * 32];
    __shared__ __align__(16) u16 Bs[128 * 32];
    const int tid = threadIdx.x;
    const int w = tid >> 6, lane = tid & 63;
    const int m0 = blockIdx.x * BM, n0 = blockIdx.y << 7;
    const int wm = (w >> 1) * (BM / 2), wn = (w & 1) << 6;
    const int row16 = lane & 15, kq = lane >> 4;
    const int srow = lane >> 2;          // 0..15 within 16-row chunk
    const int skoff = (lane & 3) << 3;   // 0,8,16,24 (bf16 elems)

    ffrag acc[MI][4] = {};

    for (int k0 = 0; k0 < K; k0 += 32) {
#pragma unroll
        for (int q = 0; q < (ACH + 8) / 4; ++q) {
            int ci = w + (q << 2);                    // 0..ACH+7
            if (ci < ACH) {
                gload_lds16(A  + (size_t)(m0 + (ci << 4) + srow) * K + k0 + skoff, As + (ci << 9));
            } else {
                int cb = ci - ACH;
                gload_lds16(Bt + (size_t)(n0 + (cb << 4) + srow) * K + k0 + skoff, Bs + (cb << 9));
            }
        }
        __syncthreads();
        bfrag af[MI], bfq[4];
#pragma unroll
        for (int i = 0; i < MI; ++i)
            af[i]  = *(const bfrag*)(As + ((wm + (i << 4) + row16) << 5) + (kq << 3));
#pragma unroll
        for (int j = 0; j < 4; ++j)
            bfq[j] = *(const bfrag*)(Bs + ((wn + (j << 4) + row16) << 5) + (kq << 3));
#pragma unroll
        for (int i = 0; i < MI; ++i)
#pragma unroll
            for (int j = 0; j < 4; ++j)
                acc[i][j] = __builtin_amdgcn_mfma_f32_16x16x32_bf16(af[i], bfq[j], acc[i][j], 0, 0, 0);
        __syncthreads();
    }

    const int crow = (lane >> 4) << 2;   // C/D: row=(lane>>4)*4+r, col=lane&15
    const int ccol = lane & 15;
#pragma unroll
    for (int i = 0; i < MI; ++i) {
        int mg = m0 + wm + (i << 4) + crow;
#pragma unroll
        for (int j = 0; j < 4; ++j) {
            int ng = n0 + wn + (j << 4) + ccol;
            if (ng < Nw) {
                float bsv = bias[ng];
#pragma unroll
                for (int r = 0; r < 4; ++r) {
                    float v = acc[i][j][r] + bsv;
                    size_t idx = (size_t)(mg + r) * ldc + ng;
                    if (res) v += res[idx];
                    if (relu) v = fmaxf(v, 0.f);
                    if (ng < elu_cols) v = (v > 0.f) ? v + 1.f : __expf(v);
                    if (Cf) Cf[idx] = v;
                    if (Cb) Cb[idx] = f2bf(v);
                }
            }
        }
    }
}

// ---------------- chunksum (MFMA): Ssum[d][e] = sum_t K[t][d]*V[t][e]; zsum[d] = sum_t K[t][d]
__global__ __launch_bounds__(256) void chunksum_kernel(
    const u16* __restrict__ qkv, float* __restrict__ Ssum, float* __restrict__ zsum)
{
    __shared__ __align__(16) u16 KT[64 * TP];   // K^T: KT[d][t]
    __shared__ __align__(16) u16 VT[64 * TP];   // V^T: VT[e][t]
    int blk = blockIdx.x;
    int c = blk % NCH; int bh = blk / NCH;
    int hh = bh % NH;  int b = bh / NH;
    const u16* kbase = qkv + ((size_t)b * SEQ + (size_t)c * CHK) * QS + DM + hh * HD;
    const u16* vbase = kbase + DM;
    const int tid = threadIdx.x;
    const int w = tid >> 6, lane = tid & 63;
    const int col = lane & 15, quad = lane >> 4;

    {   // transpose-stage K and V
        int t = tid >> 2, d0 = (tid & 3) << 4;
        bfrag k0 = *(const bfrag*)(kbase + (size_t)t * QS + d0);
        bfrag k1 = *(const bfrag*)(kbase + (size_t)t * QS + d0 + 8);
        bfrag v0 = *(const bfrag*)(vbase + (size_t)t * QS + d0);
        bfrag v1 = *(const bfrag*)(vbase + (size_t)t * QS + d0 + 8);
#pragma unroll
        for (int i = 0; i < 8; ++i) {
            KT[(d0 + i) * TP + t] = (u16)k0[i];
            KT[(d0 + 8 + i) * TP + t] = (u16)k1[i];
            VT[(d0 + i) * TP + t] = (u16)v0[i];
            VT[(d0 + 8 + i) * TP + t] = (u16)v1[i];
        }
    }
    __syncthreads();

    bfrag ktf[2];
#pragma unroll
    for (int kk = 0; kk < 2; ++kk)
        ktf[kk] = *(const bfrag*)(KT + ((w << 4) + col) * TP + kk * 32 + (quad << 3));
    bfrag ones;
#pragma unroll
    for (int i = 0; i < 8; ++i) ones[i] = (short)0x3F80;

    ffrag acc[4] = {};
    ffrag zacc = {};
#pragma unroll
    for (int j = 0; j < 4; ++j)
#pragma unroll
        for (int kk = 0; kk < 2; ++kk) {
            bfrag vf = *(const bfrag*)(VT + ((j << 4) + col) * TP + kk * 32 + (quad << 3));
            acc[j] = __builtin_amdgcn_mfma_f32_16x16x32_bf16(ktf[kk], vf, acc[j], 0, 0, 0);
        }
    zacc = __builtin_amdgcn_mfma_f32_16x16x32_bf16(ktf[0], ones, zacc, 0, 0, 0);
    zacc = __builtin_amdgcn_mfma_f32_16x16x32_bf16(ktf[1], ones, zacc, 0, 0, 0);

    float* So = Ssum + (size_t)blk * (HD * HD);
#pragma unroll
    for (int j = 0; j < 4; ++j)
#pragma unroll
        for (int r = 0; r < 4; ++r)
            So[((w << 4) + (quad << 2) + r) * HD + (j << 4) + col] = acc[j][r];
    if (col == 0) {
#pragma unroll
        for (int r = 0; r < 4; ++r)
            zsum[(size_t)blk * HD + (w << 4) + (quad << 2) + r] = zacc[r];
    }
}

// ---------------- exclusive prefix over chunks, IN PLACE on Ssum / zsum
__global__ __launch_bounds__(256) void prefix_kernel(float* __restrict__ Ssum,
                                                     float* __restrict__ zsum)
{
    int bh = blockIdx.x >> 4;
    int eg = blockIdx.x & 15;
    int entry = (eg << 8) + threadIdx.x;     // 0..4095
    size_t base = (size_t)bh * NCH * (HD * HD) + entry;
    float pre = 0.f;
    for (int c = 0; c < NCH; ++c) {
        float cur = Ssum[base + (size_t)c * (HD * HD)];
        Ssum[base + (size_t)c * (HD * HD)] = pre;
        pre += cur;
    }
    if (eg == 0 && threadIdx.x < 64) {
        size_t zb = (size_t)bh * NCH * HD + threadIdx.x;
        float zp = 0.f;
        for (int c = 0; c < NCH; ++c) {
            float cur = zsum[zb + c * HD];
            zsum[zb + c * HD] = zp;
            zp += cur;
        }
    }
}

// ---------------- attention (MFMA): out[t] = (Q@Spre + tril(QK^T)@V) / (Q.zpre + rowsum(tril(QK^T)) + eps)
__global__ __launch_bounds__(256) void attn_kernel(
    const u16* __restrict__ qkv, const float* __restrict__ Spre,
    const float* __restrict__ zpre, u16* __restrict__ ab)
{
    __shared__ __align__(16) u16 Qs[64 * 64];    // Q row-major (stride 64, global_load_lds)
    __shared__ __align__(16) u16 KP[64 * TP];    // phase A: K rows (stride 64); phase B: P rows (stride TP)
    __shared__ __align__(16) u16 VT[64 * TP];    // V^T
    __shared__ __align__(16) u16 SpT[64 * TP];   // Spre^T (bf16)
    __shared__ __align__(16) u16 zb[64];         // zpre bf16
    int blk = blockIdx.x;
    int c = blk % NCH; int bh = blk / NCH;
    int hh = bh % NH;  int b = bh / NH;
    const int tid = threadIdx.x;
    const int w = tid >> 6, lane = tid & 63;
    const int col = lane & 15, quad = lane >> 4;
    const size_t rowbase = ((size_t)b * SEQ + (size_t)c * CHK);
    const u16* qbase = qkv + rowbase * QS + hh * HD;
    const u16* vbase = qbase + 2 * DM;

    // stage Q, K via global_load_lds (rows contiguous, stride 64)
#pragma unroll
    for (int li = 0; li < 2; ++li) {
        int ld = (li << 2) + w;                  // 0..7
        int grow = (ld << 3) + (lane >> 3);      // 0..63
        int gcol = (lane & 7) << 3;
        gload_lds16(qbase + (size_t)grow * QS + gcol, Qs + (ld << 9));
        gload_lds16(qbase + DM + (size_t)grow * QS + gcol, KP + (ld << 9));
    }
    {   // transpose-stage V
        int t = tid >> 2, e0 = (tid & 3) << 4;
        bfrag v0 = *(const bfrag*)(vbase + (size_t)t * QS + e0);
        bfrag v1 = *(const bfrag*)(vbase + (size_t)t * QS + e0 + 8);
#pragma unroll
        for (int i = 0; i < 8; ++i) {
            VT[(e0 + i) * TP + t] = (u16)v0[i];
            VT[(e0 + 8 + i) * TP + t] = (u16)v1[i];
        }
    }
    {   // transpose-stage Spre (fp32 -> bf16)
        const float* sp = Spre + ((size_t)bh * NCH + c) * (HD * HD);
        int d = tid >> 2, e0 = (tid & 3) << 4;
#pragma unroll
        for (int g = 0; g < 4; ++g) {
            float4 f = *(const float4*)(sp + d * HD + e0 + (g << 2));
            SpT[(e0 + (g << 2) + 0) * TP + d] = f2bf(f.x);
            SpT[(e0 + (g << 2) + 1) * TP + d] = f2bf(f.y);
            SpT[(e0 + (g << 2) + 2) * TP + d] = f2bf(f.z);
            SpT[(e0 + (g << 2) + 3) * TP + d] = f2bf(f.w);
        }
    }
    if (tid < 64) zb[tid] = f2bf(zpre[((size_t)bh * NCH + c) * HD + tid]);
    __syncthreads();

    // Q A-frags for this wave's 16 rows (kept in regs for S, inter, den)
    bfrag qf[2];
#pragma unroll
    for (int kk = 0; kk < 2; ++kk)
        qf[kk] = *(const bfrag*)(Qs + ((w << 4) + col) * 64 + kk * 32 + (quad << 3));

    // Phase A: S tiles (rows 16w..16w+15, all 64 cols)
    ffrag S[4] = {};
#pragma unroll
    for (int j = 0; j < 4; ++j)
#pragma unroll
        for (int kk = 0; kk < 2; ++kk) {
            bfrag kf = *(const bfrag*)(KP + ((j << 4) + col) * 64 + kk * 32 + (quad << 3));
            S[j] = __builtin_amdgcn_mfma_f32_16x16x32_bf16(qf[kk], kf, S[j], 0, 0, 0);
        }
    __syncthreads();   // everyone done reading K; KP becomes P

    // mask, fp32 row-sums (pre-rounding), write P bf16
    float rs[4] = {0.f, 0.f, 0.f, 0.f};
#pragma unroll
    for (int j = 0; j < 4; ++j)
#pragma unroll
        for (int r = 0; r < 4; ++r) {
            int t = (w << 4) + (quad << 2) + r;
            int u = (j << 4) + col;
            float sv = (u <= t) ? S[j][r] : 0.f;
            rs[r] += sv;
            KP[t * TP + u] = f2bf(sv);
        }
#pragma unroll
    for (int r = 0; r < 4; ++r) {
        rs[r] += __shfl_xor(rs[r], 1);
        rs[r] += __shfl_xor(rs[r], 2);
        rs[r] += __shfl_xor(rs[r], 4);
        rs[r] += __shfl_xor(rs[r], 8);
    }

    // den: Q . zpre via column-broadcast z B-frag (C-layout rows align with O)
    ffrag dacc = {};
#pragma unroll
    for (int kk = 0; kk < 2; ++kk) {
        bfrag zf = *(const bfrag*)(zb + kk * 32 + (quad << 3));
        dacc = __builtin_amdgcn_mfma_f32_16x16x32_bf16(qf[kk], zf, dacc, 0, 0, 0);
    }

    // Phase B: O = Q @ SpreT + P @ V  (wave reads only its own P rows; DS ops in-wave are ordered)
    ffrag O[4] = {};
    bfrag pf[2];
#pragma unroll
    for (int kk = 0; kk < 2; ++kk)
        pf[kk] = *(const bfrag*)(KP + ((w << 4) + col) * TP + kk * 32 + (quad << 3));
#pragma unroll
    for (int j = 0; j < 4; ++j)
#pragma unroll
        for (int kk = 0; kk < 2; ++kk) {
            bfrag sf = *(const bfrag*)(SpT + ((j << 4) + col) * TP + kk * 32 + (quad << 3));
            O[j] = __builtin_amdgcn_mfma_f32_16x16x32_bf16(qf[kk], sf, O[j], 0, 0, 0);
            bfrag vf = *(const bfrag*)(VT + ((j << 4) + col) * TP + kk * 32 + (quad << 3));
            O[j] = __builtin_amdgcn_mfma_f32_16x16x32_bf16(pf[kk], vf, O[j], 0, 0, 0);
        }

    // epilogue
#pragma unroll
    for (int j = 0; j < 4; ++j)
#pragma unroll
        for (int r = 0; r < 4; ++r) {
            int t = (w << 4) + (quad << 2) + r;
            int e = (j << 4) + col;
            float den = dacc[r] + rs[r] + 1e-6f;
            ab[(rowbase + t) * DM + hh * HD + e] = f2bf(O[j][r] / den);
        }
}

// ---------------- LayerNorm (in-place capable): fp32 out + bf16 copy
__global__ __launch_bounds__(256) void ln_kernel(
    const float* __restrict__ in, const float* __restrict__ gg,
    const float* __restrict__ bb, float* __restrict__ out, u16* __restrict__ outb)
{
    __shared__ float red[8];
    int row = blockIdx.x, tid = threadIdx.x;
    const float* xp = in + (size_t)row * DM;
    float2 xv = *(const float2*)(xp + 2 * tid);
    float s = xv.x + xv.y;
    float sq = xv.x * xv.x + xv.y * xv.y;
#pragma unroll
    for (int off = 32; off > 0; off >>= 1) {
        s  += __shfl_down(s, off);
        sq += __shfl_down(sq, off);
    }
    if ((tid & 63) == 0) { red[tid >> 6] = s; red[4 + (tid >> 6)] = sq; }
    __syncthreads();
    float st = red[0] + red[1] + red[2] + red[3];
    float sqt = red[4] + red[5] + red[6] + red[7];
    float m = st * (1.0f / DM);
    float var = sqt * (1.0f / DM) - m * m;
    float rs = rsqrtf(var + 1e-5f);
    float2 o;
    o.x = (xv.x - m) * rs * gg[2 * tid]     + bb[2 * tid];
    o.y = (xv.y - m) * rs * gg[2 * tid + 1] + bb[2 * tid + 1];
    *(float2*)(out + (size_t)row * DM + 2 * tid) = o;
    ushort2 ob; ob.x = f2bf(o.x); ob.y = f2bf(o.y);
    *(ushort2*)(outb + (size_t)row * DM + 2 * tid) = ob;
}

extern "C" void kernel_launch(void* const* d_in, const int* in_sizes, int n_in,
                              void* d_out, int out_size, void* d_ws, size_t ws_size,
                              hipStream_t stream)
{
    (void)in_sizes; (void)n_in; (void)out_size; (void)ws_size;
    const int*   x    = (const int*)d_in[0];
    const float* emb  = (const float*)d_in[1];
    const float* Wqkv = (const float*)d_in[2];
    const float* bqkv = (const float*)d_in[3];
    const float* Wo   = (const float*)d_in[4];
    const float* bo   = (const float*)d_in[5];
    const float* ln1g = (const float*)d_in[6];
    const float* ln1b = (const float*)d_in[7];
    const float* W1   = (const float*)d_in[8];
    const float* b1   = (const float*)d_in[9];
    const float* W2   = (const float*)d_in[10];
    const float* b2   = (const float*)d_in[11];
    const float* ln2g = (const float*)d_in[12];
    const float* ln2b = (const float*)d_in[13];
    const float* lnfg = (const float*)d_in[14];
    const float* lnfb = (const float*)d_in[15];
    const float* Wout = (const float*)d_in[16];
    const float* bout = (const float*)d_in[17];

    char* p = (char*)d_ws;
    float* h     = (float*)p;  p += (size_t)MR * DM * 4;       // fp32 residual stream
    u16*  hb     = (u16*)p;    p += (size_t)MR * DM * 2;       // bf16 copy of h
    u16*  qkvb   = (u16*)p;    p += (size_t)MR * QS * 2;       // fused q|k|v bf16
    u16*  abb    = (u16*)p;    p += (size_t)MR * DM * 2;       // attn out bf16
    u16*  midb   = (u16*)p;    p += (size_t)MR * DFF * 2;      // relu(ff1) bf16
    float* Ssum  = (float*)p;  p += (size_t)NBH * NCH * HD * HD * 4;
    float* zsum  = (float*)p;  p += (size_t)NBH * NCH * HD * 4;
    u16* WqkvT   = (u16*)p;    p += (size_t)NL * 3 * DM * DM * 2;  // [l][1536][512]
    u16* WoT     = (u16*)p;    p += (size_t)NL * DM * DM * 2;      // [l][512][512]
    u16* W1T     = (u16*)p;    p += (size_t)NL * DFF * DM * 2;     // [l][2048][512]
    u16* W2T     = (u16*)p;    p += (size_t)NL * DM * DFF * 2;     // [l][512][2048]
    u16* WoutT   = (u16*)p;    p += (size_t)DM * DM * 2;           // [512pad][512]

    // ---- weight prep (every call; ws is re-poisoned)
    wtr_kernel<<<dim3(8, 8, NL * 3), 256, 0, stream>>>(Wqkv, WqkvT, DM, DM, DM);
    wtr_kernel<<<dim3(8, 8, NL), 256, 0, stream>>>(Wo, WoT, DM, DM, DM);
    wtr_kernel<<<dim3(32, 8, NL), 256, 0, stream>>>(W1, W1T, DM, DFF, DFF);
    wtr_kernel<<<dim3(8, 32, NL), 256, 0, stream>>>(W2, W2T, DFF, DM, DM);
    wtr_kernel<<<dim3(8, 8, 1), 256, 0, stream>>>(Wout, WoutT, DM, NT, DM);

    embed_kernel<<<MR, 256, 0, stream>>>(x, emb, h, hb);

    for (int l = 0; l < NL; ++l) {
        // fused QKV + bias + elu(q,k)+1, bf16 out [MR][1536]  (768 blocks, 3/CU)
        mfma_gemm<128><<<dim3(MR / 128, QS / 128), 256, 0, stream>>>(
            hb, WqkvT + (size_t)l * QS * DM, bqkv + (size_t)l * QS, nullptr,
            nullptr, qkvb, QS, DM, QS, QS, 0, 2 * DM);

        chunksum_kernel<<<NBH * NCH, 256, 0, stream>>>(qkvb, Ssum, zsum);
        prefix_kernel<<<NBH * 16, 256, 0, stream>>>(Ssum, zsum);
        attn_kernel<<<NBH * NCH, 256, 0, stream>>>(qkvb, Ssum, zsum, abb);

        // h += attn @ Wo + bo  (in-place residual; BM=64 -> 512 blocks, 2/CU)
        mfma_gemm<64><<<dim3(MR / 64, DM / 128), 256, 0, stream>>>(
            abb, WoT + (size_t)l * DM * DM, bo + (size_t)l * DM, h,
            h, nullptr, DM, DM, DM, DM, 0, 0);
        ln_kernel<<<MR, 256, 0, stream>>>(h, ln1g + (size_t)l * DM, ln1b + (size_t)l * DM, h, hb);

        // mid = relu(h @ W1 + b1), bf16  (1024 blocks, 4/CU)
        mfma_gemm<128><<<dim3(MR / 128, DFF / 128), 256, 0, stream>>>(
            hb, W1T + (size_t)l * DFF * DM, b1 + (size_t)l * DFF, nullptr,
            nullptr, midb, DFF, DM, DFF, DFF, 1, 0);
        // h += mid @ W2 + b2  (BM=64 -> 512 blocks, 2/CU)
        mfma_gemm<64><<<dim3(MR / 64, DM / 128), 256, 0, stream>>>(
            midb, W2T + (size_t)l * DM * DFF, b2 + (size_t)l * DM, h,
            h, nullptr, DM, DFF, DM, DM, 0, 0);
        ln_kernel<<<MR, 256, 0, stream>>>(h, ln2g + (size_t)l * DM, ln2b + (size_t)l * DM, h, hb);
    }

    ln_kernel<<<MR, 256, 0, stream>>>(h, lnfg, lnfb, h, hb);
    // logits = hb @ WoutT^T + bout  (N padded to 512, write 400; BM=64 -> 512 blocks)
    mfma_gemm<64><<<dim3(MR / 64, DM / 128), 256, 0, stream>>>(
        hb, WoutT, bout, nullptr, (float*)d_out, nullptr, DM, DM, NT, NT, 0, 0);
}

// Round 6
// 2267.926 us; speedup vs baseline: 5.0864x; 1.0888x over previous
//
#include <hip/hip_runtime.h>
#include <hip/hip_bf16.h>

#define DM 512
#define DFF 2048
#define NB 4
#define SEQ 2048
#define NH 8
#define HD 64
#define NL 12
#define NT 400
#define MR (NB*SEQ)      // 8192 rows
#define CHK 64           // attention chunk length
#define NCH (SEQ/CHK)    // 32 chunks
#define NBH (NB*NH)      // 32 (b,h) pairs
#define QS  (3*DM)       // fused qkv row stride = 1536
#define TP 72            // transposed-tile LDS stride (16B-aligned rows)

typedef unsigned short u16;
typedef short bfrag __attribute__((ext_vector_type(8)));   // 8 bf16 (4 VGPRs)
typedef float ffrag __attribute__((ext_vector_type(4)));   // 4 fp32 acc

__device__ __forceinline__ float bf2f(u16 u) { return __uint_as_float(((unsigned)u) << 16); }
__device__ __forceinline__ u16 f2bf(float f) {
    unsigned u = __float_as_uint(f);
    u += 0x7fffu + ((u >> 16) & 1u);   // round-to-nearest-even
    return (u16)(u >> 16);
}

__device__ __forceinline__ void gload_lds16(const u16* g, u16* l) {
    __builtin_amdgcn_global_load_lds((const __attribute__((address_space(1))) void*)g,
                                     (__attribute__((address_space(3))) void*)l, 16, 0, 0);
}

// ---------------- weight transpose+convert: in[mi][K][N] fp32 -> out[mi][Nout][K] bf16
__global__ __launch_bounds__(256) void wtr_kernel(const float* __restrict__ in,
                                                  u16* __restrict__ out,
                                                  int K, int N, int Nout)
{
    __shared__ float T[64][65];
    int n0 = blockIdx.x << 6, k0 = blockIdx.y << 6;
    const float* ip = in + (size_t)blockIdx.z * K * N;
    u16* op = out + (size_t)blockIdx.z * Nout * K;
    int c = threadIdx.x & 63, r = threadIdx.x >> 6;
#pragma unroll
    for (int i = 0; i < 16; ++i) {
        int k = k0 + 4 * i + r;
        int n = n0 + c;
        T[4 * i + r][c] = (n < N) ? ip[(size_t)k * N + n] : 0.f;
    }
    __syncthreads();
#pragma unroll
    for (int i = 0; i < 16; ++i) {
        int n = n0 + 4 * i + r;
        op[(size_t)n * K + k0 + c] = f2bf(T[c][4 * i + r]);
    }
}

// ---------------- embed: h fp32 + hb bf16
__global__ __launch_bounds__(256) void embed_kernel(const int* __restrict__ x,
                                                    const float* __restrict__ emb,
                                                    float* __restrict__ h,
                                                    u16* __restrict__ hb)
{
    int row = blockIdx.x;
    int s = row & (SEQ - 1);
    int tok = x[row];
    int j = threadIdx.x;
    float2 ev = *(const float2*)(emb + (size_t)tok * DM + 2 * j);
    const float scale = 22.627416997969522f;           // sqrt(512)
    float dv = expf((float)(2 * j) * (-9.210340371976184f / 512.0f));
    float ang = (float)s * dv;
    float2 o;
    o.x = ev.x * scale + sinf(ang);
    o.y = ev.y * scale + cosf(ang);
    *(float2*)(h + (size_t)row * DM + 2 * j) = o;
    ushort2 ob; ob.x = f2bf(o.x); ob.y = f2bf(o.y);
    *(ushort2*)(hb + (size_t)row * DM + 2 * j) = ob;
}

// ---------------- MFMA GEMM: C[M,N] = A[M,K](bf16) @ Bt[N,K]^T(bf16) + bias
// Tile BM x 128, BK=64 (two 32-col panels). Register-prefetch staging:
// global_load -> VGPRs (in flight across MFMA block; barriers don't drain
// private loads) -> ds_write (lane-linear, conflict-free) -> frag ds_read.
template<int BM>
__global__ __launch_bounds__(256) void mfma_gemm(
    const u16* __restrict__ A, const u16* __restrict__ Bt,
    const float* __restrict__ bias, const float* __restrict__ res,
    float* __restrict__ Cf, u16* __restrict__ Cb,
    int N, int K, int ldc, int Nw, int relu, int elu_cols)
{
    constexpr int MI = BM / 32;           // m-frags per wave
    constexpr int AE = BM * 64 / (256 * 8); // A bfrag chunks per thread (128->4, 64->2)
    constexpr int PA = BM * 32;           // A panel elems
    constexpr int PB = 128 * 32;          // B panel elems
    __shared__ __align__(16) u16 As[BM * 64];
    __shared__ __align__(16) u16 Bs[128 * 64];
    const int tid = threadIdx.x;
    const int w = tid >> 6, lane = tid & 63;
    const int m0 = blockIdx.x * BM, n0 = blockIdx.y << 7;
    const int wm = (w >> 1) * (BM / 2), wn = (w & 1) << 6;
    const int row16 = lane & 15, kq = lane >> 4;

    ffrag acc[MI][4] = {};
    bfrag aR[AE], bR[4];

    // initial tile load (k0 = 0)
#pragma unroll
    for (int j = 0; j < AE; ++j) {
        int o = j * 2048 + 8 * tid;
        int row = (o & (PA - 1)) >> 5;
        int col = ((o / PA) << 5) + (o & 31);
        aR[j] = *(const bfrag*)(A + (size_t)(m0 + row) * K + col);
    }
#pragma unroll
    for (int j = 0; j < 4; ++j) {
        int o = j * 2048 + 8 * tid;
        int row = (o & (PB - 1)) >> 5;
        int col = ((o / PB) << 5) + (o & 31);
        bR[j] = *(const bfrag*)(Bt + (size_t)(n0 + row) * K + col);
    }

    for (int k0 = 0; k0 < K; k0 += 64) {
        // stage regs -> LDS (lane-linear, conflict-free)
#pragma unroll
        for (int j = 0; j < AE; ++j) *(bfrag*)(As + j * 2048 + 8 * tid) = aR[j];
#pragma unroll
        for (int j = 0; j < 4; ++j)  *(bfrag*)(Bs + j * 2048 + 8 * tid) = bR[j];
        __syncthreads();
        // prefetch next tile into regs (stays in flight across MFMA block)
        if (k0 + 64 < K) {
            int kn = k0 + 64;
#pragma unroll
            for (int j = 0; j < AE; ++j) {
                int o = j * 2048 + 8 * tid;
                int row = (o & (PA - 1)) >> 5;
                int col = ((o / PA) << 5) + (o & 31);
                aR[j] = *(const bfrag*)(A + (size_t)(m0 + row) * K + kn + col);
            }
#pragma unroll
            for (int j = 0; j < 4; ++j) {
                int o = j * 2048 + 8 * tid;
                int row = (o & (PB - 1)) >> 5;
                int col = ((o / PB) << 5) + (o & 31);
                bR[j] = *(const bfrag*)(Bt + (size_t)(n0 + row) * K + kn + col);
            }
        }
        // compute from LDS
#pragma unroll
        for (int kk = 0; kk < 2; ++kk) {
            bfrag af[MI], bfq[4];
#pragma unroll
            for (int i = 0; i < MI; ++i)
                af[i]  = *(const bfrag*)(As + kk * PA + ((wm + (i << 4) + row16) << 5) + (kq << 3));
#pragma unroll
            for (int j = 0; j < 4; ++j)
                bfq[j] = *(const bfrag*)(Bs + kk * PB + ((wn + (j << 4) + row16) << 5) + (kq << 3));
#pragma unroll
            for (int i = 0; i < MI; ++i)
#pragma unroll
                for (int j = 0; j < 4; ++j)
                    acc[i][j] = __builtin_amdgcn_mfma_f32_16x16x32_bf16(af[i], bfq[j], acc[i][j], 0, 0, 0);
        }
        __syncthreads();
    }

    const int crow = (lane >> 4) << 2;   // C/D: row=(lane>>4)*4+r, col=lane&15
    const int ccol = lane & 15;
#pragma unroll
    for (int i = 0; i < MI; ++i) {
        int mg = m0 + wm + (i << 4) + crow;
#pragma unroll
        for (int j = 0; j < 4; ++j) {
            int ng = n0 + wn + (j << 4) + ccol;
            if (ng < Nw) {
                float bsv = bias[ng];
#pragma unroll
                for (int r = 0; r < 4; ++r) {
                    float v = acc[i][j][r] + bsv;
                    size_t idx = (size_t)(mg + r) * ldc + ng;
                    if (res) v += res[idx];
                    if (relu) v = fmaxf(v, 0.f);
                    if (ng < elu_cols) v = (v > 0.f) ? v + 1.f : __expf(v);
                    if (Cf) Cf[idx] = v;
                    if (Cb) Cb[idx] = f2bf(v);
                }
            }
        }
    }
}

// ---------------- chunksum (MFMA): Ssum[d][e] = sum_t K[t][d]*V[t][e]; zsum[d] = sum_t K[t][d]
__global__ __launch_bounds__(256) void chunksum_kernel(
    const u16* __restrict__ qkv, float* __restrict__ Ssum, float* __restrict__ zsum)
{
    __shared__ __align__(16) u16 KT[64 * TP];   // K^T: KT[d][t]
    __shared__ __align__(16) u16 VT[64 * TP];   // V^T: VT[e][t]
    int blk = blockIdx.x;
    int c = blk % NCH; int bh = blk / NCH;
    int hh = bh % NH;  int b = bh / NH;
    const u16* kbase = qkv + ((size_t)b * SEQ + (size_t)c * CHK) * QS + DM + hh * HD;
    const u16* vbase = kbase + DM;
    const int tid = threadIdx.x;
    const int w = tid >> 6, lane = tid & 63;
    const int col = lane & 15, quad = lane >> 4;

    {   // transpose-stage K and V
        int t = tid >> 2, d0 = (tid & 3) << 4;
        bfrag k0 = *(const bfrag*)(kbase + (size_t)t * QS + d0);
        bfrag k1 = *(const bfrag*)(kbase + (size_t)t * QS + d0 + 8);
        bfrag v0 = *(const bfrag*)(vbase + (size_t)t * QS + d0);
        bfrag v1 = *(const bfrag*)(vbase + (size_t)t * QS + d0 + 8);
#pragma unroll
        for (int i = 0; i < 8; ++i) {
            KT[(d0 + i) * TP + t] = (u16)k0[i];
            KT[(d0 + 8 + i) * TP + t] = (u16)k1[i];
            VT[(d0 + i) * TP + t] = (u16)v0[i];
            VT[(d0 + 8 + i) * TP + t] = (u16)v1[i];
        }
    }
    __syncthreads();

    bfrag ktf[2];
#pragma unroll
    for (int kk = 0; kk < 2; ++kk)
        ktf[kk] = *(const bfrag*)(KT + ((w << 4) + col) * TP + kk * 32 + (quad << 3));
    bfrag ones;
#pragma unroll
    for (int i = 0; i < 8; ++i) ones[i] = (short)0x3F80;

    ffrag acc[4] = {};
    ffrag zacc = {};
#pragma unroll
    for (int j = 0; j < 4; ++j)
#pragma unroll
        for (int kk = 0; kk < 2; ++kk) {
            bfrag vf = *(const bfrag*)(VT + ((j << 4) + col) * TP + kk * 32 + (quad << 3));
            acc[j] = __builtin_amdgcn_mfma_f32_16x16x32_bf16(ktf[kk], vf, acc[j], 0, 0, 0);
        }
    zacc = __builtin_amdgcn_mfma_f32_16x16x32_bf16(ktf[0], ones, zacc, 0, 0, 0);
    zacc = __builtin_amdgcn_mfma_f32_16x16x32_bf16(ktf[1], ones, zacc, 0, 0, 0);

    float* So = Ssum + (size_t)blk * (HD * HD);
#pragma unroll
    for (int j = 0; j < 4; ++j)
#pragma unroll
        for (int r = 0; r < 4; ++r)
            So[((w << 4) + (quad << 2) + r) * HD + (j << 4) + col] = acc[j][r];
    if (col == 0) {
#pragma unroll
        for (int r = 0; r < 4; ++r)
            zsum[(size_t)blk * HD + (w << 4) + (quad << 2) + r] = zacc[r];
    }
}

// ---------------- exclusive prefix over chunks, IN PLACE on Ssum / zsum
__global__ __launch_bounds__(256) void prefix_kernel(float* __restrict__ Ssum,
                                                     float* __restrict__ zsum)
{
    int bh = blockIdx.x >> 4;
    int eg = blockIdx.x & 15;
    int entry = (eg << 8) + threadIdx.x;     // 0..4095
    size_t base = (size_t)bh * NCH * (HD * HD) + entry;
    float pre = 0.f;
    for (int c = 0; c < NCH; ++c) {
        float cur = Ssum[base + (size_t)c * (HD * HD)];
        Ssum[base + (size_t)c * (HD * HD)] = pre;
        pre += cur;
    }
    if (eg == 0 && threadIdx.x < 64) {
        size_t zb = (size_t)bh * NCH * HD + threadIdx.x;
        float zp = 0.f;
        for (int c = 0; c < NCH; ++c) {
            float cur = zsum[zb + c * HD];
            zsum[zb + c * HD] = zp;
            zp += cur;
        }
    }
}

// ---------------- attention (MFMA): out[t] = (Q@Spre + tril(QK^T)@V) / (Q.zpre + rowsum(tril(QK^T)) + eps)
__global__ __launch_bounds__(256) void attn_kernel(
    const u16* __restrict__ qkv, const float* __restrict__ Spre,
    const float* __restrict__ zpre, u16* __restrict__ ab)
{
    __shared__ __align__(16) u16 Qs[64 * 64];    // Q row-major (stride 64, global_load_lds)
    __shared__ __align__(16) u16 KP[64 * TP];    // phase A: K rows (stride 64); phase B: P rows (stride TP)
    __shared__ __align__(16) u16 VT[64 * TP];    // V^T
    __shared__ __align__(16) u16 SpT[64 * TP];   // Spre^T (bf16)
    __shared__ __align__(16) u16 zb[64];         // zpre bf16
    int blk = blockIdx.x;
    int c = blk % NCH; int bh = blk / NCH;
    int hh = bh % NH;  int b = bh / NH;
    const int tid = threadIdx.x;
    const int w = tid >> 6, lane = tid & 63;
    const int col = lane & 15, quad = lane >> 4;
    const size_t rowbase = ((size_t)b * SEQ + (size_t)c * CHK);
    const u16* qbase = qkv + rowbase * QS + hh * HD;
    const u16* vbase = qbase + 2 * DM;

    // stage Q, K via global_load_lds (rows contiguous, stride 64)
#pragma unroll
    for (int li = 0; li < 2; ++li) {
        int ld = (li << 2) + w;                  // 0..7
        int grow = (ld << 3) + (lane >> 3);      // 0..63
        int gcol = (lane & 7) << 3;
        gload_lds16(qbase + (size_t)grow * QS + gcol, Qs + (ld << 9));
        gload_lds16(qbase + DM + (size_t)grow * QS + gcol, KP + (ld << 9));
    }
    {   // transpose-stage V
        int t = tid >> 2, e0 = (tid & 3) << 4;
        bfrag v0 = *(const bfrag*)(vbase + (size_t)t * QS + e0);
        bfrag v1 = *(const bfrag*)(vbase + (size_t)t * QS + e0 + 8);
#pragma unroll
        for (int i = 0; i < 8; ++i) {
            VT[(e0 + i) * TP + t] = (u16)v0[i];
            VT[(e0 + 8 + i) * TP + t] = (u16)v1[i];
        }
    }
    {   // transpose-stage Spre (fp32 -> bf16)
        const float* sp = Spre + ((size_t)bh * NCH + c) * (HD * HD);
        int d = tid >> 2, e0 = (tid & 3) << 4;
#pragma unroll
        for (int g = 0; g < 4; ++g) {
            float4 f = *(const float4*)(sp + d * HD + e0 + (g << 2));
            SpT[(e0 + (g << 2) + 0) * TP + d] = f2bf(f.x);
            SpT[(e0 + (g << 2) + 1) * TP + d] = f2bf(f.y);
            SpT[(e0 + (g << 2) + 2) * TP + d] = f2bf(f.z);
            SpT[(e0 + (g << 2) + 3) * TP + d] = f2bf(f.w);
        }
    }
    if (tid < 64) zb[tid] = f2bf(zpre[((size_t)bh * NCH + c) * HD + tid]);
    __syncthreads();

    // Q A-frags for this wave's 16 rows (kept in regs for S, inter, den)
    bfrag qf[2];
#pragma unroll
    for (int kk = 0; kk < 2; ++kk)
        qf[kk] = *(const bfrag*)(Qs + ((w << 4) + col) * 64 + kk * 32 + (quad << 3));

    // Phase A: S tiles (rows 16w..16w+15, all 64 cols)
    ffrag S[4] = {};
#pragma unroll
    for (int j = 0; j < 4; ++j)
#pragma unroll
        for (int kk = 0; kk < 2; ++kk) {
            bfrag kf = *(const bfrag*)(KP + ((j << 4) + col) * 64 + kk * 32 + (quad << 3));
            S[j] = __builtin_amdgcn_mfma_f32_16x16x32_bf16(qf[kk], kf, S[j], 0, 0, 0);
        }
    __syncthreads();   // everyone done reading K; KP becomes P

    // mask, fp32 row-sums (pre-rounding), write P bf16
    float rs[4] = {0.f, 0.f, 0.f, 0.f};
#pragma unroll
    for (int j = 0; j < 4; ++j)
#pragma unroll
        for (int r = 0; r < 4; ++r) {
            int t = (w << 4) + (quad << 2) + r;
            int u = (j << 4) + col;
            float sv = (u <= t) ? S[j][r] : 0.f;
            rs[r] += sv;
            KP[t * TP + u] = f2bf(sv);
        }
#pragma unroll
    for (int r = 0; r < 4; ++r) {
        rs[r] += __shfl_xor(rs[r], 1);
        rs[r] += __shfl_xor(rs[r], 2);
        rs[r] += __shfl_xor(rs[r], 4);
        rs[r] += __shfl_xor(rs[r], 8);
    }

    // den: Q . zpre via column-broadcast z B-frag (C-layout rows align with O)
    ffrag dacc = {};
#pragma unroll
    for (int kk = 0; kk < 2; ++kk) {
        bfrag zf = *(const bfrag*)(zb + kk * 32 + (quad << 3));
        dacc = __builtin_amdgcn_mfma_f32_16x16x32_bf16(qf[kk], zf, dacc, 0, 0, 0);
    }

    // Phase B: O = Q @ SpreT + P @ V  (wave reads only its own P rows; DS ops in-wave are ordered)
    ffrag O[4] = {};
    bfrag pf[2];
#pragma unroll
    for (int kk = 0; kk < 2; ++kk)
        pf[kk] = *(const bfrag*)(KP + ((w << 4) + col) * TP + kk * 32 + (quad << 3));
#pragma unroll
    for (int j = 0; j < 4; ++j)
#pragma unroll
        for (int kk = 0; kk < 2; ++kk) {
            bfrag sf = *(const bfrag*)(SpT + ((j << 4) + col) * TP + kk * 32 + (quad << 3));
            O[j] = __builtin_amdgcn_mfma_f32_16x16x32_bf16(qf[kk], sf, O[j], 0, 0, 0);
            bfrag vf = *(const bfrag*)(VT + ((j << 4) + col) * TP + kk * 32 + (quad << 3));
            O[j] = __builtin_amdgcn_mfma_f32_16x16x32_bf16(pf[kk], vf, O[j], 0, 0, 0);
        }

    // epilogue
#pragma unroll
    for (int j = 0; j < 4; ++j)
#pragma unroll
        for (int r = 0; r < 4; ++r) {
            int t = (w << 4) + (quad << 2) + r;
            int e = (j << 4) + col;
            float den = dacc[r] + rs[r] + 1e-6f;
            ab[(rowbase + t) * DM + hh * HD + e] = f2bf(O[j][r] / den);
        }
}

// ---------------- LayerNorm (in-place capable): fp32 out + bf16 copy
__global__ __launch_bounds__(256) void ln_kernel(
    const float* __restrict__ in, const float* __restrict__ gg,
    const float* __restrict__ bb, float* __restrict__ out, u16* __restrict__ outb)
{
    __shared__ float red[8];
    int row = blockIdx.x, tid = threadIdx.x;
    const float* xp = in + (size_t)row * DM;
    float2 xv = *(const float2*)(xp + 2 * tid);
    float s = xv.x + xv.y;
    float sq = xv.x * xv.x + xv.y * xv.y;
#pragma unroll
    for (int off = 32; off > 0; off >>= 1) {
        s  += __shfl_down(s, off);
        sq += __shfl_down(sq, off);
    }
    if ((tid & 63) == 0) { red[tid >> 6] = s; red[4 + (tid >> 6)] = sq; }
    __syncthreads();
    float st = red[0] + red[1] + red[2] + red[3];
    float sqt = red[4] + red[5] + red[6] + red[7];
    float m = st * (1.0f / DM);
    float var = sqt * (1.0f / DM) - m * m;
    float rs = rsqrtf(var + 1e-5f);
    float2 o;
    o.x = (xv.x - m) * rs * gg[2 * tid]     + bb[2 * tid];
    o.y = (xv.y - m) * rs * gg[2 * tid + 1] + bb[2 * tid + 1];
    *(float2*)(out + (size_t)row * DM + 2 * tid) = o;
    ushort2 ob; ob.x = f2bf(o.x); ob.y = f2bf(o.y);
    *(ushort2*)(outb + (size_t)row * DM + 2 * tid) = ob;
}

extern "C" void kernel_launch(void* const* d_in, const int* in_sizes, int n_in,
                              void* d_out, int out_size, void* d_ws, size_t ws_size,
                              hipStream_t stream)
{
    (void)in_sizes; (void)n_in; (void)out_size; (void)ws_size;
    const int*   x    = (const int*)d_in[0];
    const float* emb  = (const float*)d_in[1];
    const float* Wqkv = (const float*)d_in[2];
    const float* bqkv = (const float*)d_in[3];
    const float* Wo   = (const float*)d_in[4];
    const float* bo   = (const float*)d_in[5];
    const float* ln1g = (const float*)d_in[6];
    const float* ln1b = (const float*)d_in[7];
    const float* W1   = (const float*)d_in[8];
    const float* b1   = (const float*)d_in[9];
    const float* W2   = (const float*)d_in[10];
    const float* b2   = (const float*)d_in[11];
    const float* ln2g = (const float*)d_in[12];
    const float* ln2b = (const float*)d_in[13];
    const float* lnfg = (const float*)d_in[14];
    const float* lnfb = (const float*)d_in[15];
    const float* Wout = (const float*)d_in[16];
    const float* bout = (const float*)d_in[17];

    char* p = (char*)d_ws;
    float* h     = (float*)p;  p += (size_t)MR * DM * 4;       // fp32 residual stream
    u16*  hb     = (u16*)p;    p += (size_t)MR * DM * 2;       // bf16 copy of h
    u16*  qkvb   = (u16*)p;    p += (size_t)MR * QS * 2;       // fused q|k|v bf16
    u16*  abb    = (u16*)p;    p += (size_t)MR * DM * 2;       // attn out bf16
    u16*  midb   = (u16*)p;    p += (size_t)MR * DFF * 2;      // relu(ff1) bf16
    float* Ssum  = (float*)p;  p += (size_t)NBH * NCH * HD * HD * 4;
    float* zsum  = (float*)p;  p += (size_t)NBH * NCH * HD * 4;
    u16* WqkvT   = (u16*)p;    p += (size_t)NL * 3 * DM * DM * 2;  // [l][1536][512]
    u16* WoT     = (u16*)p;    p += (size_t)NL * DM * DM * 2;      // [l][512][512]
    u16* W1T     = (u16*)p;    p += (size_t)NL * DFF * DM * 2;     // [l][2048][512]
    u16* W2T     = (u16*)p;    p += (size_t)NL * DM * DFF * 2;     // [l][512][2048]
    u16* WoutT   = (u16*)p;    p += (size_t)DM * DM * 2;           // [512pad][512]

    // ---- weight prep (every call; ws is re-poisoned)
    wtr_kernel<<<dim3(8, 8, NL * 3), 256, 0, stream>>>(Wqkv, WqkvT, DM, DM, DM);
    wtr_kernel<<<dim3(8, 8, NL), 256, 0, stream>>>(Wo, WoT, DM, DM, DM);
    wtr_kernel<<<dim3(32, 8, NL), 256, 0, stream>>>(W1, W1T, DM, DFF, DFF);
    wtr_kernel<<<dim3(8, 32, NL), 256, 0, stream>>>(W2, W2T, DFF, DM, DM);
    wtr_kernel<<<dim3(8, 8, 1), 256, 0, stream>>>(Wout, WoutT, DM, NT, DM);

    embed_kernel<<<MR, 256, 0, stream>>>(x, emb, h, hb);

    for (int l = 0; l < NL; ++l) {
        // fused QKV + bias + elu(q,k)+1, bf16 out [MR][1536]  (768 blocks, 3/CU)
        mfma_gemm<128><<<dim3(MR / 128, QS / 128), 256, 0, stream>>>(
            hb, WqkvT + (size_t)l * QS * DM, bqkv + (size_t)l * QS, nullptr,
            nullptr, qkvb, QS, DM, QS, QS, 0, 2 * DM);

        chunksum_kernel<<<NBH * NCH, 256, 0, stream>>>(qkvb, Ssum, zsum);
        prefix_kernel<<<NBH * 16, 256, 0, stream>>>(Ssum, zsum);
        attn_kernel<<<NBH * NCH, 256, 0, stream>>>(qkvb, Ssum, zsum, abb);

        // h += attn @ Wo + bo  (in-place residual; BM=64 -> 512 blocks, 2/CU)
        mfma_gemm<64><<<dim3(MR / 64, DM / 128), 256, 0, stream>>>(
            abb, WoT + (size_t)l * DM * DM, bo + (size_t)l * DM, h,
            h, nullptr, DM, DM, DM, DM, 0, 0);
        ln_kernel<<<MR, 256, 0, stream>>>(h, ln1g + (size_t)l * DM, ln1b + (size_t)l * DM, h, hb);

        // mid = relu(h @ W1 + b1), bf16  (1024 blocks, 4/CU)
        mfma_gemm<128><<<dim3(MR / 128, DFF / 128), 256, 0, stream>>>(
            hb, W1T + (size_t)l * DFF * DM, b1 + (size_t)l * DFF, nullptr,
            nullptr, midb, DFF, DM, DFF, DFF, 1, 0);
        // h += mid @ W2 + b2  (BM=64 -> 512 blocks, 2/CU)
        mfma_gemm<64><<<dim3(MR / 64, DM / 128), 256, 0, stream>>>(
            midb, W2T + (size_t)l * DM * DFF, b2 + (size_t)l * DM, h,
            h, nullptr, DM, DFF, DM, DM, 0, 0);
        ln_kernel<<<MR, 256, 0, stream>>>(h, ln2g + (size_t)l * DM, ln2b + (size_t)l * DM, h, hb);
    }

    ln_kernel<<<MR, 256, 0, stream>>>(h, lnfg, lnfb, h, hb);
    // logits = hb @ WoutT^T + bout  (N padded to 512, write 400; BM=64 -> 512 blocks)
    mfma_gemm<64><<<dim3(MR / 64, DM / 128), 256, 0, stream>>>(
        hb, WoutT, bout, nullptr, (float*)d_out, nullptr, DM, DM, NT, NT, 0, 0);
}